// Round 7
// baseline (1954.127 us; speedup 1.0000x reference)
//
#include <hip/hip_runtime.h>

typedef unsigned short u16;
typedef __attribute__((ext_vector_type(4))) float f32x4;
typedef __attribute__((ext_vector_type(8))) __bf16 bf16x8;
typedef __attribute__((ext_vector_type(4))) unsigned short u16x4;

static __device__ __forceinline__ u16 f2bf(float f) {
  union { float f; unsigned u; } v; v.f = f;
  unsigned r = v.u + 0x7fffu + ((v.u >> 16) & 1u);
  return (u16)(r >> 16);
}

#define GLD_LDS(g, l) __builtin_amdgcn_global_load_lds( \
    (const __attribute__((address_space(1))) void*)(g), \
    (__attribute__((address_space(3))) void*)(l), 16, 0, 0)

#define LGKM0() asm volatile("s_waitcnt lgkmcnt(0)" ::: "memory")
#define SBAR() do { __builtin_amdgcn_sched_barrier(0); \
                    __builtin_amdgcn_s_barrier(); \
                    __builtin_amdgcn_sched_barrier(0); } while (0)

// ---------------------------------------------------------------------------
// 128x128-tile BK=32 4-wave GEMM, occupancy-first (3-4 blocks/CU) with
// T2 swizzle (2-way banks = free), counted vmcnt, setprio.
// C = A[M,K] @ Bt[N,K]^T. LDS 32 KB: [buf][A 128x32 | B 128x32], 16B units;
// data(row, slot) stored at dslot = slot ^ ((row>>1)&3) (pre-swizzled global
// source, swizzled ds_read, linear gload_lds dest - rule #21).
// Pipeline per K-tile: vmcnt(4) [kt's 4 loads landed, kt+1's in flight];
// barrier; ds_read 8 frags; lgkm0; barrier (all waves done reading buf);
// stage kt+2 into buf; 16 MFMA. vmcnt(0) only on the last tile.
// EPI: 0 = Cf = alpha*acc + bias; 2 = Cb = bf16(acc+bias); 3 = bf16 relu.
// ---------------------------------------------------------------------------
template<int EPI>
__global__ __launch_bounds__(256, 3)
void gemm4w(const u16* __restrict__ A, const u16* __restrict__ B,
            float* __restrict__ Cf, u16* __restrict__ Cb,
            const float* __restrict__ bias, float alpha,
            int K, int lda, int ldb, int ldc, int mtiles, int gm, int nsplit,
            long long sA, long long sB, long long sC)
{
  __shared__ u16 lds[16384];  // 32 KB: buf*8192 + {A:0, B:4096}
  const int t = threadIdx.x;
  const int w = t >> 6, l = t & 63;
  const int l15 = l & 15, l16 = l >> 4;
  const int wr = w >> 1, wc = w & 1;

  int wg = blockIdx.x;
  const int nwg = gridDim.x;
  {
    const int q = nwg >> 3, r = nwg & 7;
    const int xcd = wg & 7, loc = wg >> 3;
    wg = (xcd < r ? xcd * (q + 1) : r * (q + 1) + (xcd - r) * q) + loc;
  }
  const int ntiles = nwg / mtiles;
  const int gsz = gm * ntiles;
  const int gi = wg / gsz;
  const int rr = wg - gi * gsz;
  const int nt = rr / gm;
  const int mt = gi * gm + (rr - nt * gm);
  const int m0 = mt << 7, n0 = nt << 7;

  const int bz = blockIdx.z;
  int batch = bz, sp = 0;
  if (nsplit > 1) { batch = bz / nsplit; sp = bz - batch * nsplit; }
  const u16* Ab = A + (long long)batch * sA + (long long)sp * K + m0 * (long long)lda;
  const u16* Bb = B + (long long)batch * sB + (long long)sp * K + n0 * (long long)ldb;
  const long long cbase = (long long)bz * sC;

  // staging geometry: unit u = w*128 + j*64 + l covers row u>>2, dest slot u&3,
  // source slot (u&3)^((row>>1)&3). Dest passed to gload_lds is wave-uniform
  // (HW adds lane*16).
  const u16* pa[2]; const u16* pb[2];
  int sdst[2];
#pragma unroll
  for (int j = 0; j < 2; ++j) {
    const int u = w * 128 + j * 64 + l;
    const int row = u >> 2;
    const int sl = (u & 3) ^ ((row >> 1) & 3);
    sdst[j] = (w * 128 + j * 64) * 8;  // wave-uniform elem offset
    pa[j] = Ab + (long long)row * lda + sl * 8;
    pb[j] = Bb + (long long)row * ldb + sl * 8;
  }
  auto STAGE = [&](int buf) {
#pragma unroll
    for (int j = 0; j < 2; ++j) { GLD_LDS(pa[j], &lds[buf * 8192 + sdst[j]]); pa[j] += 32; }
#pragma unroll
    for (int j = 0; j < 2; ++j) { GLD_LDS(pb[j], &lds[buf * 8192 + 4096 + sdst[j]]); pb[j] += 32; }
  };

  const int nkt = K >> 5;
  STAGE(0);
  if (nkt > 1) STAGE(1);

  f32x4 acc[4][4] = {};

  for (int kt = 0; kt < nkt; ++kt) {
    const int buf = kt & 1;
    if (kt + 1 < nkt) asm volatile("s_waitcnt vmcnt(4)" ::: "memory");
    else              asm volatile("s_waitcnt vmcnt(0)" ::: "memory");
    SBAR();
    bf16x8 af[4], bg[4];
#pragma unroll
    for (int mf = 0; mf < 4; ++mf) {
      const int r2 = wr * 64 + mf * 16 + l15;
      af[mf] = *(const bf16x8*)&lds[buf * 8192 + r2 * 32 + (l16 ^ ((r2 >> 1) & 3)) * 8];
    }
#pragma unroll
    for (int nf = 0; nf < 4; ++nf) {
      const int r2 = wc * 64 + nf * 16 + l15;
      bg[nf] = *(const bf16x8*)&lds[buf * 8192 + 4096 + r2 * 32 + (l16 ^ ((r2 >> 1) & 3)) * 8];
    }
    LGKM0();
    __builtin_amdgcn_sched_barrier(0);
    SBAR();  // all waves done reading buf -> safe to overwrite
    if (kt + 2 < nkt) STAGE(buf);
    __builtin_amdgcn_s_setprio(1);
#pragma unroll
    for (int mf = 0; mf < 4; ++mf)
#pragma unroll
      for (int nf = 0; nf < 4; ++nf)
        acc[mf][nf] = __builtin_amdgcn_mfma_f32_16x16x32_bf16(af[mf], bg[nf], acc[mf][nf], 0, 0, 0);
    __builtin_amdgcn_s_setprio(0);
  }

#pragma unroll
  for (int mf = 0; mf < 4; ++mf) {
    const int rbase = m0 + wr * 64 + mf * 16 + l16 * 4;
#pragma unroll
    for (int nf = 0; nf < 4; ++nf) {
      const int col = n0 + wc * 64 + nf * 16 + l15;
      const float bv = bias ? bias[col] : 0.f;
#pragma unroll
      for (int r = 0; r < 4; ++r) {
        const long long idx = cbase + (long long)(rbase + r) * ldc + col;
        const float v = acc[mf][nf][r];
        if (EPI == 0)      Cf[idx] = alpha * v + bv;
        else if (EPI == 2) Cb[idx] = f2bf(v + bv);
        else               { float x = v + bv; Cb[idx] = f2bf(x > 0.f ? x : 0.f); }
      }
    }
  }
}

// ---- legacy 128x128 engine (small shapes: QKV, headWd) ----
template<int EPI>
__global__ __launch_bounds__(256)
void gemm_bt(const u16* __restrict__ A, const u16* __restrict__ B,
             float* __restrict__ Cf, u16* __restrict__ Cb,
             const float* __restrict__ bias, float alpha,
             int K, int lda, int ldb, int ldc, int mtiles, int gm, int nsplit,
             long long sA, long long sB, long long sC)
{
  __shared__ u16 ldsA[128 * 32];
  __shared__ u16 ldsB[128 * 32];
  const int t = threadIdx.x;
  const int w = t >> 6, l = t & 63;

  int wg = blockIdx.x;
  const int nwg = gridDim.x;
  {
    const int q = nwg >> 3, r = nwg & 7;
    const int xcd = wg & 7, loc = wg >> 3;
    wg = (xcd < r ? xcd * (q + 1) : r * (q + 1) + (xcd - r) * q) + loc;
  }
  const int ntiles = nwg / mtiles;
  const int gsz = gm * ntiles;
  const int gi = wg / gsz;
  const int rr = wg - gi * gsz;
  const int nt = rr / gm;
  const int mt = gi * gm + (rr - nt * gm);
  const int m0 = mt << 7, n0 = nt << 7;

  const int bzRaw = blockIdx.z;
  int batch = bzRaw, sp = 0;
  if (nsplit > 1) { batch = bzRaw / nsplit; sp = bzRaw - batch * nsplit; }
  const u16* Ab = A + (long long)batch * sA + (long long)sp * K;
  const u16* Bb = B + (long long)batch * sB + (long long)sp * K;
  const long long cbase = (long long)bzRaw * sC;

  const int wr = (w >> 1) << 6, wc = (w & 1) << 6;
  const int l15 = l & 15, l16 = l >> 4;
  f32x4 acc[4][4] = {};

  for (int k0 = 0; k0 < K; k0 += 32) {
#pragma unroll
    for (int r = 0; r < 2; ++r) {
      const int o = (r << 12) + (t << 4);
      const int row = o >> 6;
      const int cole = (o & 63) >> 1;
      GLD_LDS(Ab + (long long)(m0 + row) * lda + k0 + cole, &ldsA[(r << 11) + (w << 9)]);
      GLD_LDS(Bb + (long long)(n0 + row) * ldb + k0 + cole, &ldsB[(r << 11) + (w << 9)]);
    }
    __syncthreads();
    bf16x8 af[4], bg[4];
#pragma unroll
    for (int i = 0; i < 4; ++i) {
      af[i] = *(const bf16x8*)&ldsA[(wr + i * 16 + l15) * 32 + l16 * 8];
      bg[i] = *(const bf16x8*)&ldsB[(wc + i * 16 + l15) * 32 + l16 * 8];
    }
#pragma unroll
    for (int i = 0; i < 4; ++i)
#pragma unroll
      for (int j = 0; j < 4; ++j)
        acc[i][j] = __builtin_amdgcn_mfma_f32_16x16x32_bf16(af[i], bg[j], acc[i][j], 0, 0, 0);
    __syncthreads();
  }

#pragma unroll
  for (int i = 0; i < 4; ++i) {
    const int rbase = m0 + wr + i * 16 + l16 * 4;
#pragma unroll
    for (int j = 0; j < 4; ++j) {
      const int col = n0 + wc + j * 16 + l15;
      const float bv = bias ? bias[col] : 0.f;
#pragma unroll
      for (int r = 0; r < 4; ++r) {
        const long long idx = cbase + (long long)(rbase + r) * ldc + col;
        const float v = acc[i][j][r];
        if (EPI == 0)      Cf[idx] = alpha * v + bv;
        else if (EPI == 1) Cf[idx] += v + bv;
        else if (EPI == 2) Cb[idx] = f2bf(v + bv);
        else               { float x = v + bv; Cb[idx] = f2bf(x > 0.f ? x : 0.f); }
      }
    }
  }
}

// ---------------- fused flash attention ----------------
__device__ __forceinline__ void fstep(
    const bf16x8 (&ck)[4][2], const bf16x8 (&cv)[4][2],
    bf16x8 (&nk)[4][2], bf16x8 (&nv)[4][2],
    const bf16x8 (&qf)[2], float (&m)[4], float (&ls)[4], f32x4 (&o)[4],
    const u16* qb, const u16* vb, int kv0, int kvn, u16* pl, int l15, int l16)
{
  f32x4 s[4] = {};
#pragma unroll
  for (int ni = 0; ni < 4; ++ni)
#pragma unroll
    for (int kk = 0; kk < 2; ++kk)
      s[ni] = __builtin_amdgcn_mfma_f32_16x16x32_bf16(qf[kk], ck[ni][kk], s[ni], 0, 0, 0);
#pragma unroll
  for (int ni = 0; ni < 4; ++ni)
#pragma unroll
    for (int kk = 0; kk < 2; ++kk)
      nk[ni][kk] = *(const bf16x8*)(qb + (kvn + ni * 16 + l15) * 256 + 64 + kk * 32 + l16 * 8);
#pragma unroll
  for (int ni = 0; ni < 4; ++ni) s[ni] *= 0.125f;
  float al[4], ps[4];
#pragma unroll
  for (int r = 0; r < 4; ++r) {
    float v = fmaxf(fmaxf(s[0][r], s[1][r]), fmaxf(s[2][r], s[3][r]));
    v = fmaxf(v, __shfl_xor(v, 1)); v = fmaxf(v, __shfl_xor(v, 2));
    v = fmaxf(v, __shfl_xor(v, 4)); v = fmaxf(v, __shfl_xor(v, 8));
    const float mn = fmaxf(m[r], v);
    al[r] = __expf(m[r] - mn);
    m[r] = mn;
    ps[r] = 0.f;
  }
#pragma unroll
  for (int ni = 0; ni < 4; ++ni)
#pragma unroll
    for (int r = 0; r < 4; ++r) {
      const float p = __expf(s[ni][r] - m[r]);
      ps[r] += p;
      pl[(l16 * 4 + r) * 72 + ni * 16 + l15] = f2bf(p);
    }
#pragma unroll
  for (int r = 0; r < 4; ++r) {
    float t = ps[r];
    t += __shfl_xor(t, 1); t += __shfl_xor(t, 2);
    t += __shfl_xor(t, 4); t += __shfl_xor(t, 8);
    ls[r] = ls[r] * al[r] + t;
  }
#pragma unroll
  for (int nd = 0; nd < 4; ++nd)
#pragma unroll
    for (int r = 0; r < 4; ++r) o[nd][r] *= al[r];
  bf16x8 pa[2];
#pragma unroll
  for (int kk = 0; kk < 2; ++kk)
    pa[kk] = *(const bf16x8*)&pl[l15 * 72 + kk * 32 + l16 * 8];
#pragma unroll
  for (int nd = 0; nd < 4; ++nd)
#pragma unroll
    for (int kk = 0; kk < 2; ++kk)
      o[nd] = __builtin_amdgcn_mfma_f32_16x16x32_bf16(pa[kk], cv[nd][kk], o[nd], 0, 0, 0);
#pragma unroll
  for (int nd = 0; nd < 4; ++nd)
#pragma unroll
    for (int kk = 0; kk < 2; ++kk)
      nv[nd][kk] = *(const bf16x8*)(vb + (nd * 16 + l15) * 2048 + kvn + kk * 32 + l16 * 8);
  (void)kv0;
}

__global__ __launch_bounds__(64)
void flash_k(const u16* __restrict__ qkv, const u16* __restrict__ vT,
             u16* __restrict__ head)
{
  __shared__ u16 pl[16 * 72];
  const int l = threadIdx.x, l15 = l & 15, l16 = l >> 4;
  const int b = blockIdx.x >> 7, q0 = (blockIdx.x & 127) << 4;
  const u16* qb = qkv + (long long)b * 2048 * 256;
  const u16* vb = vT + (long long)b * 64 * 2048;
  bf16x8 qf[2];
#pragma unroll
  for (int kk = 0; kk < 2; ++kk)
    qf[kk] = *(const bf16x8*)(qb + (q0 + l15) * 256 + kk * 32 + l16 * 8);
  float m[4], ls[4];
  f32x4 o[4] = {};
#pragma unroll
  for (int r = 0; r < 4; ++r) { m[r] = -1e30f; ls[r] = 0.f; }
  bf16x8 ka[4][2], va[4][2], kb[4][2], vb2[4][2];
#pragma unroll
  for (int ni = 0; ni < 4; ++ni)
#pragma unroll
    for (int kk = 0; kk < 2; ++kk) {
      ka[ni][kk] = *(const bf16x8*)(qb + (ni * 16 + l15) * 256 + 64 + kk * 32 + l16 * 8);
      va[ni][kk] = *(const bf16x8*)(vb + (ni * 16 + l15) * 2048 + kk * 32 + l16 * 8);
    }
  for (int t = 0; t < 32; t += 2) {
    fstep(ka, va, kb, vb2, qf, m, ls, o, qb, vb, t * 64, (t + 1) * 64, pl, l15, l16);
    fstep(kb, vb2, ka, va, qf, m, ls, o, qb, vb, (t + 1) * 64,
          (t + 2 < 32 ? (t + 2) * 64 : 31 * 64), pl, l15, l16);
  }
#pragma unroll
  for (int nd = 0; nd < 4; ++nd)
#pragma unroll
    for (int r = 0; r < 4; ++r)
      head[((long long)b * 2048 + q0 + l16 * 4 + r) * 64 + nd * 16 + l15] =
          f2bf(o[nd][r] / ls[r]);
}

// LayerNorm over rows of 1024 f32 -> bf16 out
__global__ __launch_bounds__(256)
void ln_k(const float* __restrict__ x, const float* __restrict__ g,
          const float* __restrict__ b, u16* __restrict__ z)
{
  const long long row = blockIdx.x;
  f32x4 v = ((const f32x4*)(x + row * 1024))[threadIdx.x];
  float s = v[0] + v[1] + v[2] + v[3];
  float q = v[0] * v[0] + v[1] * v[1] + v[2] * v[2] + v[3] * v[3];
#pragma unroll
  for (int o = 32; o; o >>= 1) { s += __shfl_down(s, o); q += __shfl_down(q, o); }
  __shared__ float rs_[4], rq_[4];
  const int l = threadIdx.x & 63, w = threadIdx.x >> 6;
  if (l == 0) { rs_[w] = s; rq_[w] = q; }
  __syncthreads();
  s = rs_[0] + rs_[1] + rs_[2] + rs_[3];
  q = rq_[0] + rq_[1] + rq_[2] + rq_[3];
  const float mu = s * (1.f / 1024.f);
  const float rstd = rsqrtf(q * (1.f / 1024.f) - mu * mu + 1e-5f);
  const f32x4 gv = ((const f32x4*)g)[threadIdx.x];
  const f32x4 bv = ((const f32x4*)b)[threadIdx.x];
  u16x4 o4;
#pragma unroll
  for (int e = 0; e < 4; ++e) o4[e] = f2bf((v[e] - mu) * rstd * gv[e] + bv[e]);
  ((u16x4*)(z + row * 1024))[threadIdx.x] = o4;
}

// fused: hnew = h + sum_{s<4} bf16partial_s + c2 ; MODE0: h=hnew, z=LN(hnew);
// MODE1: z=bf16(hnew) (h dead)
template<int MODE>
__global__ __launch_bounds__(256)
void reduce_ln_k(const u16* __restrict__ p, float* __restrict__ h,
                 const float* __restrict__ c2, const float* __restrict__ g,
                 const float* __restrict__ b, u16* __restrict__ z)
{
  const long long row = blockIdx.x;
  const int t = threadIdx.x;
  const long long i4 = (row << 8) + t;
  f32x4 v = ((const f32x4*)h)[i4] + ((const f32x4*)c2)[t];
#pragma unroll
  for (int s = 0; s < 4; ++s) {
    u16x4 pv = ((const u16x4*)p)[i4 + (long long)s * 1048576];
#pragma unroll
    for (int e = 0; e < 4; ++e) {
      union { unsigned u; float f; } x; x.u = ((unsigned)pv[e]) << 16;
      v[e] += x.f;
    }
  }
  u16x4 o4;
  if (MODE == 1) {
#pragma unroll
    for (int e = 0; e < 4; ++e) o4[e] = f2bf(v[e]);
  } else {
    ((f32x4*)h)[i4] = v;
    float s = v[0] + v[1] + v[2] + v[3];
    float q = v[0] * v[0] + v[1] * v[1] + v[2] * v[2] + v[3] * v[3];
#pragma unroll
    for (int o = 32; o; o >>= 1) { s += __shfl_down(s, o); q += __shfl_down(q, o); }
    __shared__ float rs_[4], rq_[4];
    const int l = t & 63, w = t >> 6;
    if (l == 0) { rs_[w] = s; rq_[w] = q; }
    __syncthreads();
    s = rs_[0] + rs_[1] + rs_[2] + rs_[3];
    q = rq_[0] + rq_[1] + rq_[2] + rq_[3];
    const float mu = s * (1.f / 1024.f);
    const float rstd = rsqrtf(q * (1.f / 1024.f) - mu * mu + 1e-5f);
    const f32x4 gv = ((const f32x4*)g)[t];
    const f32x4 bv = ((const f32x4*)b)[t];
#pragma unroll
    for (int e = 0; e < 4; ++e) o4[e] = f2bf((v[e] - mu) * rstd * gv[e] + bv[e]);
  }
  ((u16x4*)z)[i4] = o4;
}

__global__ __launch_bounds__(256)
void gather_k(const int* __restrict__ x, const float* __restrict__ emb, float* __restrict__ h)
{
  const long long tok = blockIdx.x;
  const long long r = (long long)x[tok] << 8;
  ((f32x4*)h)[(tok << 8) + threadIdx.x] = ((const f32x4*)emb)[r + threadIdx.x];
}

// f32 [R][C] -> bf16 [C][R]
__global__ __launch_bounds__(256)
void tcast_k(const float* __restrict__ in, u16* __restrict__ out, int R, int C)
{
  __shared__ float tile[32][33];
  const int tx = threadIdx.x & 31, ty = threadIdx.x >> 5;
  const long long r0 = (long long)blockIdx.y << 5, c0 = (long long)blockIdx.x << 5;
#pragma unroll
  for (int yy = 0; yy < 32; yy += 8)
    tile[ty + yy][tx] = in[(r0 + ty + yy) * C + c0 + tx];
  __syncthreads();
#pragma unroll
  for (int yy = 0; yy < 32; yy += 8)
    out[(c0 + ty + yy) * R + r0 + tx] = f2bf(tile[tx][ty + yy]);
}

__global__ __launch_bounds__(256)
void wqkv_k(const float* __restrict__ Wq, const float* __restrict__ Wk,
            const float* __restrict__ Wv, u16* __restrict__ o)
{
  const int n = blockIdx.y;
  const long long e = (long long)blockIdx.x * 256 + threadIdx.x;
  float v = 0.f;
  if (n < 64)       v = Wq[e * 64 + n];
  else if (n < 128) v = Wk[e * 64 + (n - 64)];
  else if (n < 192) v = Wv[e * 64 + (n - 128)];
  o[(long long)n * 1024 + e] = f2bf(v);
}

__global__ __launch_bounds__(256)
void bqkv_k(const float* __restrict__ bq, const float* __restrict__ bk,
            const float* __restrict__ bv, float* __restrict__ o)
{
  const int n = threadIdx.x;
  float v = 0.f;
  if (n < 64)       v = bq[n];
  else if (n < 128) v = bk[n - 64];
  else if (n < 192) v = bv[n - 128];
  o[n] = v;
}

__global__ __launch_bounds__(256)
void wdsum_k(const float* __restrict__ Wd, u16* __restrict__ o)
{
  const int i = blockIdx.x * 256 + threadIdx.x;
  const int a = i & 63, e = i >> 6;
  float s = 0.f;
#pragma unroll
  for (int hh = 0; hh < 16; ++hh) s += Wd[(long long)(hh * 64 + a) * 1024 + e];
  o[i] = f2bf(s);
}

// qkv = bf16(p0+p1+bqkv), plus vT scatter for v-cols [128,192) -> vT[b*64+a][2048]
__global__ __launch_bounds__(256)
void reduce_qkv(const float* __restrict__ p, const float* __restrict__ bqkv,
                u16* __restrict__ qkv, u16* __restrict__ vT)
{
  const long long i4 = (long long)blockIdx.x * 256 + threadIdx.x;
  const int c4 = (int)(i4 & 63);
  const long long row = i4 >> 6;
  f32x4 s = ((const f32x4*)p)[i4] + ((const f32x4*)p)[i4 + 262144]
          + ((const f32x4*)bqkv)[c4];
  u16x4 o;
#pragma unroll
  for (int e = 0; e < 4; ++e) o[e] = f2bf(s[e]);
  ((u16x4*)qkv)[i4] = o;
  if (c4 >= 32 && c4 < 48) {
    const long long b = row >> 11, sidx = row & 2047;
#pragma unroll
    for (int e = 0; e < 4; ++e) {
      const int a = (c4 - 32) * 4 + e;
      vT[(b * 64 + a) * 2048 + sidx] = o[e];
    }
  }
}

extern "C" void kernel_launch(void* const* d_in, const int* in_sizes, int n_in,
                              void* d_out, int out_size, void* d_ws, size_t ws_size,
                              hipStream_t stream) {
  const int*   x   = (const int*)d_in[0];
  const float* emb = (const float*)d_in[1];
  const float* Wq  = (const float*)d_in[2];
  const float* bq  = (const float*)d_in[3];
  const float* Wk  = (const float*)d_in[4];
  const float* bk  = (const float*)d_in[5];
  const float* Wv  = (const float*)d_in[6];
  const float* bv  = (const float*)d_in[7];
  const float* Wd  = (const float*)d_in[8];
  const float* bd  = (const float*)d_in[9];
  const float* g1  = (const float*)d_in[10];
  const float* be1 = (const float*)d_in[11];
  const float* g2  = (const float*)d_in[12];
  const float* be2 = (const float*)d_in[13];
  const float* W1  = (const float*)d_in[14];
  const float* c1  = (const float*)d_in[15];
  const float* W2  = (const float*)d_in[16];
  const float* c2  = (const float*)d_in[17];
  const float* Wfc = (const float*)d_in[18];
  const float* bfc = (const float*)d_in[19];
  float* out = (float*)d_out;

  char* ws = (char*)d_ws;
  size_t off = 0;
  auto alloc = [&](size_t bytes) { void* p = ws + off; off = (off + bytes + 255) & ~(size_t)255; return p; };
  float*  h     = (float*) alloc(4096ull * 1024 * 4);
  u16*    z     = (u16*)   alloc(4096ull * 1024 * 2);
  u16*    qkv   = (u16*)   alloc(4096ull * 256 * 2);
  u16*    vT    = (u16*)   alloc(2ull * 64 * 2048 * 2);
  u16*    head  = (u16*)   alloc(4096ull * 64 * 2);
  u16*    mid   = (u16*)   alloc(4096ull * 4096 * 2);
  char*   SCR   = (char*)  alloc(2ull * 4096 * 1024 * 4);
  float*  partQ = (float*)SCR;
  u16*    partF = (u16*)SCR;
  u16*    Wqkvt = (u16*)   alloc(256ull * 1024 * 2);
  float*  bqkv  = (float*) alloc(256 * 4);
  u16*    Wdst  = (u16*)   alloc(1024ull * 64 * 2);
  u16*    W1t   = (u16*)   alloc(4096ull * 1024 * 2);
  u16*    W2t   = (u16*)   alloc(1024ull * 4096 * 2);
  u16*    Wfct  = (u16*)   alloc(32000ull * 1024 * 2);

  // ---- prep (every launch; no caching allowed) ----
  gather_k<<<4096, 256, 0, stream>>>(x, emb, h);
  wqkv_k<<<dim3(4, 256), 256, 0, stream>>>(Wq, Wk, Wv, Wqkvt);
  bqkv_k<<<1, 256, 0, stream>>>(bq, bk, bv, bqkv);
  wdsum_k<<<256, 256, 0, stream>>>(Wd, Wdst);
  tcast_k<<<dim3(128, 32), 256, 0, stream>>>(W1, W1t, 1024, 4096);
  tcast_k<<<dim3(32, 128), 256, 0, stream>>>(W2, W2t, 4096, 1024);
  tcast_k<<<dim3(1000, 32), 256, 0, stream>>>(Wfc, Wfct, 1024, 32000);

  for (int layer = 0; layer < 8; ++layer) {
    if (layer == 0)
      ln_k<<<4096, 256, 0, stream>>>(h, g1, be1, z);
    gemm_bt<0><<<dim3(64, 1, 2), 256, 0, stream>>>(z, Wqkvt, partQ, nullptr, nullptr, 1.f,
        512, 1024, 1024, 256, 32, 32, 2, 0, 0, 1048576);
    reduce_qkv<<<1024, 256, 0, stream>>>(partQ, bqkv, qkv, vT);
    flash_k<<<256, 64, 0, stream>>>(qkv, vT, head);
    gemm_bt<1><<<dim3(256, 1, 1), 256, 0, stream>>>(head, Wdst, h, nullptr, bd, 1.f,
        64, 64, 64, 1024, 32, 32, 1, 0, 0, 0);
    ln_k<<<4096, 256, 0, stream>>>(h, g2, be2, z);
    // mid = relu(z2 @ W1 + c1) -- 4-wave occupancy engine
    gemm4w<3><<<dim3(1024, 1, 1), 256, 0, stream>>>(z, W1t, nullptr, mid, c1, 1.f,
        1024, 1024, 1024, 4096, 32, 16, 1, 0, 0, 0);
    // partF[sp] = bf16(mid @ W2^T) (split-K x4, K=1024 each)
    gemm4w<2><<<dim3(256, 1, 4), 256, 0, stream>>>(mid, W2t, nullptr, partF, nullptr, 1.f,
        1024, 4096, 4096, 1024, 32, 16, 4, 0, 0, 4194304);
    if (layer < 7)
      reduce_ln_k<0><<<4096, 256, 0, stream>>>(partF, h, c2, g1, be1, z);
    else
      reduce_ln_k<1><<<4096, 256, 0, stream>>>(partF, h, c2, nullptr, nullptr, z);
  }
  // out = hb @ Wfc + bfc -- 4-wave occupancy engine, grouped gm=16
  gemm4w<0><<<dim3(8000, 1, 1), 256, 0, stream>>>(z, Wfct, out, nullptr, bfc, 1.f,
      1024, 1024, 1024, 32000, 32, 16, 1, 0, 0, 0);
}

// Round 8
// 1806.750 us; speedup vs baseline: 1.0816x; 1.0816x over previous
//
#include <hip/hip_runtime.h>

typedef unsigned short u16;
typedef __attribute__((ext_vector_type(4))) float f32x4;
typedef __attribute__((ext_vector_type(8))) __bf16 bf16x8;
typedef __attribute__((ext_vector_type(4))) unsigned short u16x4;

static __device__ __forceinline__ u16 f2bf(float f) {
  union { float f; unsigned u; } v; v.f = f;
  unsigned r = v.u + 0x7fffu + ((v.u >> 16) & 1u);
  return (u16)(r >> 16);
}

#define GLD_LDS(g, l) __builtin_amdgcn_global_load_lds( \
    (const __attribute__((address_space(1))) void*)(g), \
    (__attribute__((address_space(3))) void*)(l), 16, 0, 0)

// ---------------------------------------------------------------------------
// R5 engine (best measured): 256x256 BK=64 8-wave, 2-phase/K-tile, T2 swizzle
// (conflicts=0), counted vmcnt(8), setprio. 128 KB LDS, 1 block/CU.
// EPI: 0 = Cf = alpha*acc + bias; 2 = Cb = bf16(acc+bias); 3 = bf16 relu.
// ---------------------------------------------------------------------------
template<int EPI>
__global__ __launch_bounds__(512, 2)
void gemm8p(const u16* __restrict__ A, const u16* __restrict__ B,
            float* __restrict__ Cf, u16* __restrict__ Cb,
            const float* __restrict__ bias, float alpha,
            int K, int lda, int ldb, int ldc, int mtiles, int gm, int nsplit,
            long long sA, long long sB, long long sC)
{
  extern __shared__ u16 lds8[];
  const int t = threadIdx.x;
  const int w = t >> 6, l = t & 63;
  const int l15 = l & 15, l16 = l >> 4;
  const int wr = w >> 2, wc = w & 3;

  int wg = blockIdx.x;
  const int nwg = gridDim.x;
  {
    const int q = nwg >> 3, r = nwg & 7;
    const int xcd = wg & 7, loc = wg >> 3;
    wg = (xcd < r ? xcd * (q + 1) : r * (q + 1) + (xcd - r) * q) + loc;
  }
  const int ntiles = nwg / mtiles;
  const int gsz = gm * ntiles;
  const int gi = wg / gsz;
  const int rr = wg - gi * gsz;
  const int nt = rr / gm;
  const int mt = gi * gm + (rr - nt * gm);
  const int m0 = mt << 8, n0 = nt << 8;

  const int bz = blockIdx.z;
  int batch = bz, sp = 0;
  if (nsplit > 1) { batch = bz / nsplit; sp = bz - batch * nsplit; }
  const u16* Ab = A + (long long)batch * sA + (long long)sp * K;
  const u16* Bb = B + (long long)batch * sB + (long long)sp * K;
  const long long cbase = (long long)bz * sC;

  const int srow = t >> 3;
  const int scol = (((t & 7) ^ (srow & 7)) << 3);
  const u16* gA[4]; const u16* gB[4];
#pragma unroll
  for (int i = 0; i < 4; ++i) {
    gA[i] = Ab + (long long)(m0 + i * 64 + srow) * lda + scol;
    gB[i] = Bb + (long long)(n0 + i * 64 + srow) * ldb + scol;
  }
  const int ldst = w << 9;

  auto STAGE = [&](int buf) {
#pragma unroll
    for (int i = 0; i < 4; ++i) {
      GLD_LDS(gA[i], &lds8[buf * 16384 + i * 4096 + ldst]);
      gA[i] += 64;
    }
#pragma unroll
    for (int i = 0; i < 4; ++i) {
      GLD_LDS(gB[i], &lds8[32768 + buf * 16384 + i * 4096 + ldst]);
      gB[i] += 64;
    }
  };

  STAGE(0);
  STAGE(1);

  f32x4 acc[8][4] = {};
  const int nkt = K >> 6;
  const int aRow = wr * 128 + l15;
  const int bRow = wc * 64 + l15;
  const int swz = l15 & 7;

  for (int kt = 0; kt < nkt; ++kt) {
    const int buf = kt & 1;
    if (kt < nkt - 1) asm volatile("s_waitcnt vmcnt(8)" ::: "memory");
    else              asm volatile("s_waitcnt vmcnt(0)" ::: "memory");
    __builtin_amdgcn_s_barrier();
    __builtin_amdgcn_sched_barrier(0);

    const int abase = buf * 16384;
    const int bbase = 32768 + buf * 16384;
    bf16x8 af[4][2], bf[4][2];
#pragma unroll
    for (int mf = 0; mf < 4; ++mf)
#pragma unroll
      for (int kk = 0; kk < 2; ++kk)
        af[mf][kk] = *(const bf16x8*)&lds8[abase + (aRow + mf * 16) * 64 + ((((kk << 2) + l16)) ^ swz) * 8];
#pragma unroll
    for (int nf = 0; nf < 4; ++nf)
#pragma unroll
      for (int kk = 0; kk < 2; ++kk)
        bf[nf][kk] = *(const bf16x8*)&lds8[bbase + (bRow + nf * 16) * 64 + ((((kk << 2) + l16)) ^ swz) * 8];

    __builtin_amdgcn_s_setprio(1);
#pragma unroll
    for (int mf = 0; mf < 4; ++mf)
#pragma unroll
      for (int nf = 0; nf < 4; ++nf)
#pragma unroll
        for (int kk = 0; kk < 2; ++kk)
          acc[mf][nf] = __builtin_amdgcn_mfma_f32_16x16x32_bf16(af[mf][kk], bf[nf][kk], acc[mf][nf], 0, 0, 0);
    __builtin_amdgcn_s_setprio(0);

    bf16x8 ah[4][2];
#pragma unroll
    for (int mf = 0; mf < 4; ++mf)
#pragma unroll
      for (int kk = 0; kk < 2; ++kk)
        ah[mf][kk] = *(const bf16x8*)&lds8[abase + (aRow + 64 + mf * 16) * 64 + ((((kk << 2) + l16)) ^ swz) * 8];

    asm volatile("s_waitcnt lgkmcnt(0)" ::: "memory");
    __builtin_amdgcn_s_barrier();
    __builtin_amdgcn_sched_barrier(0);
    if (kt + 2 < nkt) STAGE(buf);

    __builtin_amdgcn_s_setprio(1);
#pragma unroll
    for (int mf = 0; mf < 4; ++mf)
#pragma unroll
      for (int nf = 0; nf < 4; ++nf)
#pragma unroll
        for (int kk = 0; kk < 2; ++kk)
          acc[mf + 4][nf] = __builtin_amdgcn_mfma_f32_16x16x32_bf16(ah[mf][kk], bf[nf][kk], acc[mf + 4][nf], 0, 0, 0);
    __builtin_amdgcn_s_setprio(0);
  }

#pragma unroll
  for (int mf = 0; mf < 8; ++mf) {
    const int rbase = m0 + wr * 128 + mf * 16 + l16 * 4;
#pragma unroll
    for (int nf = 0; nf < 4; ++nf) {
      const int col = n0 + wc * 64 + nf * 16 + l15;
      const float bv = bias ? bias[col] : 0.f;
#pragma unroll
      for (int r = 0; r < 4; ++r) {
        const long long idx = cbase + (long long)(rbase + r) * ldc + col;
        const float v = acc[mf][nf][r];
        if (EPI == 0)      Cf[idx] = alpha * v + bv;
        else if (EPI == 2) Cb[idx] = f2bf(v + bv);
        else               { float x = v + bv; Cb[idx] = f2bf(x > 0.f ? x : 0.f); }
      }
    }
  }
}

// ---- legacy 128x128 engine (small shapes: QKV, headWd) ----
template<int EPI>
__global__ __launch_bounds__(256)
void gemm_bt(const u16* __restrict__ A, const u16* __restrict__ B,
             float* __restrict__ Cf, u16* __restrict__ Cb,
             const float* __restrict__ bias, float alpha,
             int K, int lda, int ldb, int ldc, int mtiles, int gm, int nsplit,
             long long sA, long long sB, long long sC)
{
  __shared__ u16 ldsA[128 * 32];
  __shared__ u16 ldsB[128 * 32];
  const int t = threadIdx.x;
  const int w = t >> 6, l = t & 63;

  int wg = blockIdx.x;
  const int nwg = gridDim.x;
  {
    const int q = nwg >> 3, r = nwg & 7;
    const int xcd = wg & 7, loc = wg >> 3;
    wg = (xcd < r ? xcd * (q + 1) : r * (q + 1) + (xcd - r) * q) + loc;
  }
  const int ntiles = nwg / mtiles;
  const int gsz = gm * ntiles;
  const int gi = wg / gsz;
  const int rr = wg - gi * gsz;
  const int nt = rr / gm;
  const int mt = gi * gm + (rr - nt * gm);
  const int m0 = mt << 7, n0 = nt << 7;

  const int bzRaw = blockIdx.z;
  int batch = bzRaw, sp = 0;
  if (nsplit > 1) { batch = bzRaw / nsplit; sp = bzRaw - batch * nsplit; }
  const u16* Ab = A + (long long)batch * sA + (long long)sp * K;
  const u16* Bb = B + (long long)batch * sB + (long long)sp * K;
  const long long cbase = (long long)bzRaw * sC;

  const int wr = (w >> 1) << 6, wc = (w & 1) << 6;
  const int l15 = l & 15, l16 = l >> 4;
  f32x4 acc[4][4] = {};

  for (int k0 = 0; k0 < K; k0 += 32) {
#pragma unroll
    for (int r = 0; r < 2; ++r) {
      const int o = (r << 12) + (t << 4);
      const int row = o >> 6;
      const int cole = (o & 63) >> 1;
      GLD_LDS(Ab + (long long)(m0 + row) * lda + k0 + cole, &ldsA[(r << 11) + (w << 9)]);
      GLD_LDS(Bb + (long long)(n0 + row) * ldb + k0 + cole, &ldsB[(r << 11) + (w << 9)]);
    }
    __syncthreads();
    bf16x8 af[4], bg[4];
#pragma unroll
    for (int i = 0; i < 4; ++i) {
      af[i] = *(const bf16x8*)&ldsA[(wr + i * 16 + l15) * 32 + l16 * 8];
      bg[i] = *(const bf16x8*)&ldsB[(wc + i * 16 + l15) * 32 + l16 * 8];
    }
#pragma unroll
    for (int i = 0; i < 4; ++i)
#pragma unroll
      for (int j = 0; j < 4; ++j)
        acc[i][j] = __builtin_amdgcn_mfma_f32_16x16x32_bf16(af[i], bg[j], acc[i][j], 0, 0, 0);
    __syncthreads();
  }

#pragma unroll
  for (int i = 0; i < 4; ++i) {
    const int rbase = m0 + wr + i * 16 + l16 * 4;
#pragma unroll
    for (int j = 0; j < 4; ++j) {
      const int col = n0 + wc + j * 16 + l15;
      const float bv = bias ? bias[col] : 0.f;
#pragma unroll
      for (int r = 0; r < 4; ++r) {
        const long long idx = cbase + (long long)(rbase + r) * ldc + col;
        const float v = acc[i][j][r];
        if (EPI == 0)      Cf[idx] = alpha * v + bv;
        else if (EPI == 1) Cf[idx] += v + bv;
        else if (EPI == 2) Cb[idx] = f2bf(v + bv);
        else               { float x = v + bv; Cb[idx] = f2bf(x > 0.f ? x : 0.f); }
      }
    }
  }
}

// ---------------- fused flash attention, split-KV x4 ----------------
__device__ __forceinline__ void fstep(
    const bf16x8 (&ck)[4][2], const bf16x8 (&cv)[4][2],
    bf16x8 (&nk)[4][2], bf16x8 (&nv)[4][2],
    const bf16x8 (&qf)[2], float (&m)[4], float (&ls)[4], f32x4 (&o)[4],
    const u16* qb, const u16* vb, int kvn, u16* pl, int l15, int l16)
{
  f32x4 s[4] = {};
#pragma unroll
  for (int ni = 0; ni < 4; ++ni)
#pragma unroll
    for (int kk = 0; kk < 2; ++kk)
      s[ni] = __builtin_amdgcn_mfma_f32_16x16x32_bf16(qf[kk], ck[ni][kk], s[ni], 0, 0, 0);
#pragma unroll
  for (int ni = 0; ni < 4; ++ni)
#pragma unroll
    for (int kk = 0; kk < 2; ++kk)
      nk[ni][kk] = *(const bf16x8*)(qb + (kvn + ni * 16 + l15) * 256 + 64 + kk * 32 + l16 * 8);
#pragma unroll
  for (int ni = 0; ni < 4; ++ni) s[ni] *= 0.125f;
  float al[4], ps[4];
#pragma unroll
  for (int r = 0; r < 4; ++r) {
    float v = fmaxf(fmaxf(s[0][r], s[1][r]), fmaxf(s[2][r], s[3][r]));
    v = fmaxf(v, __shfl_xor(v, 1)); v = fmaxf(v, __shfl_xor(v, 2));
    v = fmaxf(v, __shfl_xor(v, 4)); v = fmaxf(v, __shfl_xor(v, 8));
    const float mn = fmaxf(m[r], v);
    al[r] = __expf(m[r] - mn);
    m[r] = mn;
    ps[r] = 0.f;
  }
#pragma unroll
  for (int ni = 0; ni < 4; ++ni)
#pragma unroll
    for (int r = 0; r < 4; ++r) {
      const float p = __expf(s[ni][r] - m[r]);
      ps[r] += p;
      pl[(l16 * 4 + r) * 72 + ni * 16 + l15] = f2bf(p);
    }
#pragma unroll
  for (int r = 0; r < 4; ++r) {
    float t = ps[r];
    t += __shfl_xor(t, 1); t += __shfl_xor(t, 2);
    t += __shfl_xor(t, 4); t += __shfl_xor(t, 8);
    ls[r] = ls[r] * al[r] + t;
  }
#pragma unroll
  for (int nd = 0; nd < 4; ++nd)
#pragma unroll
    for (int r = 0; r < 4; ++r) o[nd][r] *= al[r];
  bf16x8 pa[2];
#pragma unroll
  for (int kk = 0; kk < 2; ++kk)
    pa[kk] = *(const bf16x8*)&pl[l15 * 72 + kk * 32 + l16 * 8];
#pragma unroll
  for (int nd = 0; nd < 4; ++nd)
#pragma unroll
    for (int kk = 0; kk < 2; ++kk)
      o[nd] = __builtin_amdgcn_mfma_f32_16x16x32_bf16(pa[kk], cv[nd][kk], o[nd], 0, 0, 0);
#pragma unroll
  for (int nd = 0; nd < 4; ++nd)
#pragma unroll
    for (int kk = 0; kk < 2; ++kk)
      nv[nd][kk] = *(const bf16x8*)(vb + (nd * 16 + l15) * 2048 + kvn + kk * 32 + l16 * 8);
}

// grid 1024 = b(2) x sp(4) x qt(128); 1 wave. Each: 16 q-rows, kv [sp*512,+512).
// Partials: po[pidx][16][64] f32, pm/pls[pidx][16]; pidx = (b*128+qt)*4+sp.
__global__ __launch_bounds__(64)
void flashp_k(const u16* __restrict__ qkv, const u16* __restrict__ vT,
              float* __restrict__ po, float* __restrict__ pm, float* __restrict__ pls)
{
  __shared__ u16 pl[16 * 72];
  const int l = threadIdx.x, l15 = l & 15, l16 = l >> 4;
  const int idx = blockIdx.x;
  const int b = idx >> 9, rest = idx & 511, sp = rest >> 7, qt = rest & 127;
  const int q0 = qt << 4, kvb = sp << 9;
  const u16* qb = qkv + (long long)b * 2048 * 256;
  const u16* vb = vT + (long long)b * 64 * 2048;
  bf16x8 qf[2];
#pragma unroll
  for (int kk = 0; kk < 2; ++kk)
    qf[kk] = *(const bf16x8*)(qb + (q0 + l15) * 256 + kk * 32 + l16 * 8);
  float m[4], ls[4];
  f32x4 o[4] = {};
#pragma unroll
  for (int r = 0; r < 4; ++r) { m[r] = -1e30f; ls[r] = 0.f; }
  bf16x8 ka[4][2], va[4][2], kb[4][2], vb2[4][2];
#pragma unroll
  for (int ni = 0; ni < 4; ++ni)
#pragma unroll
    for (int kk = 0; kk < 2; ++kk) {
      ka[ni][kk] = *(const bf16x8*)(qb + (kvb + ni * 16 + l15) * 256 + 64 + kk * 32 + l16 * 8);
      va[ni][kk] = *(const bf16x8*)(vb + (ni * 16 + l15) * 2048 + kvb + kk * 32 + l16 * 8);
    }
  for (int ti = 0; ti < 8; ti += 2) {
    const int n1 = kvb + (ti + 1 < 8 ? (ti + 1) * 64 : 7 * 64);
    const int n2 = kvb + (ti + 2 < 8 ? (ti + 2) * 64 : 7 * 64);
    fstep(ka, va, kb, vb2, qf, m, ls, o, qb, vb, n1, pl, l15, l16);
    fstep(kb, vb2, ka, va, qf, m, ls, o, qb, vb, n2, pl, l15, l16);
  }
  const long long pidx = ((long long)(b * 128 + qt)) * 4 + sp;
#pragma unroll
  for (int nd = 0; nd < 4; ++nd)
#pragma unroll
    for (int r = 0; r < 4; ++r)
      po[pidx * 1024 + (l16 * 4 + r) * 64 + nd * 16 + l15] = o[nd][r];
  if (l15 == 0) {
#pragma unroll
    for (int r = 0; r < 4; ++r) {
      pm[pidx * 16 + l16 * 4 + r] = m[r];
      pls[pidx * 16 + l16 * 4 + r] = ls[r];
    }
  }
}

// grid 256 = b*128+qt; 64 threads (thread = output dim d).
__global__ __launch_bounds__(64)
void fmerge_k(const float* __restrict__ po, const float* __restrict__ pm,
              const float* __restrict__ pls, u16* __restrict__ head)
{
  const int idx = blockIdx.x;
  const int d = threadIdx.x;
  const long long base = (long long)idx * 4;
#pragma unroll
  for (int r = 0; r < 16; ++r) {
    float M = -1e30f;
#pragma unroll
    for (int sp = 0; sp < 4; ++sp) M = fmaxf(M, pm[(base + sp) * 16 + r]);
    float L = 0.f, acc = 0.f;
#pragma unroll
    for (int sp = 0; sp < 4; ++sp) {
      const float e = __expf(pm[(base + sp) * 16 + r] - M);
      L += pls[(base + sp) * 16 + r] * e;
      acc += po[(base + sp) * 1024 + r * 64 + d] * e;
    }
    head[((long long)idx * 16 + r) * 64 + d] = f2bf(acc / L);
  }
}

// LayerNorm over rows of 1024 f32 -> bf16 out
__global__ __launch_bounds__(256)
void ln_k(const float* __restrict__ x, const float* __restrict__ g,
          const float* __restrict__ b, u16* __restrict__ z)
{
  const long long row = blockIdx.x;
  f32x4 v = ((const f32x4*)(x + row * 1024))[threadIdx.x];
  float s = v[0] + v[1] + v[2] + v[3];
  float q = v[0] * v[0] + v[1] * v[1] + v[2] * v[2] + v[3] * v[3];
#pragma unroll
  for (int o = 32; o; o >>= 1) { s += __shfl_down(s, o); q += __shfl_down(q, o); }
  __shared__ float rs_[4], rq_[4];
  const int l = threadIdx.x & 63, w = threadIdx.x >> 6;
  if (l == 0) { rs_[w] = s; rq_[w] = q; }
  __syncthreads();
  s = rs_[0] + rs_[1] + rs_[2] + rs_[3];
  q = rq_[0] + rq_[1] + rq_[2] + rq_[3];
  const float mu = s * (1.f / 1024.f);
  const float rstd = rsqrtf(q * (1.f / 1024.f) - mu * mu + 1e-5f);
  const f32x4 gv = ((const f32x4*)g)[threadIdx.x];
  const f32x4 bv = ((const f32x4*)b)[threadIdx.x];
  u16x4 o4;
#pragma unroll
  for (int e = 0; e < 4; ++e) o4[e] = f2bf((v[e] - mu) * rstd * gv[e] + bv[e]);
  ((u16x4*)(z + row * 1024))[threadIdx.x] = o4;
}

// fused: hnew = h + sum_{s<4} bf16partial_s + c2 ; MODE0: h=hnew, z=LN(hnew);
// MODE1: z=bf16(hnew) (h dead)
template<int MODE>
__global__ __launch_bounds__(256)
void reduce_ln_k(const u16* __restrict__ p, float* __restrict__ h,
                 const float* __restrict__ c2, const float* __restrict__ g,
                 const float* __restrict__ b, u16* __restrict__ z)
{
  const long long row = blockIdx.x;
  const int t = threadIdx.x;
  const long long i4 = (row << 8) + t;
  f32x4 v = ((const f32x4*)h)[i4] + ((const f32x4*)c2)[t];
#pragma unroll
  for (int s = 0; s < 4; ++s) {
    u16x4 pv = ((const u16x4*)p)[i4 + (long long)s * 1048576];
#pragma unroll
    for (int e = 0; e < 4; ++e) {
      union { unsigned u; float f; } x; x.u = ((unsigned)pv[e]) << 16;
      v[e] += x.f;
    }
  }
  u16x4 o4;
  if (MODE == 1) {
#pragma unroll
    for (int e = 0; e < 4; ++e) o4[e] = f2bf(v[e]);
  } else {
    ((f32x4*)h)[i4] = v;
    float s = v[0] + v[1] + v[2] + v[3];
    float q = v[0] * v[0] + v[1] * v[1] + v[2] * v[2] + v[3] * v[3];
#pragma unroll
    for (int o = 32; o; o >>= 1) { s += __shfl_down(s, o); q += __shfl_down(q, o); }
    __shared__ float rs_[4], rq_[4];
    const int l = t & 63, w = t >> 6;
    if (l == 0) { rs_[w] = s; rq_[w] = q; }
    __syncthreads();
    s = rs_[0] + rs_[1] + rs_[2] + rs_[3];
    q = rq_[0] + rq_[1] + rq_[2] + rq_[3];
    const float mu = s * (1.f / 1024.f);
    const float rstd = rsqrtf(q * (1.f / 1024.f) - mu * mu + 1e-5f);
    const f32x4 gv = ((const f32x4*)g)[t];
    const f32x4 bv = ((const f32x4*)b)[t];
#pragma unroll
    for (int e = 0; e < 4; ++e) o4[e] = f2bf((v[e] - mu) * rstd * gv[e] + bv[e]);
  }
  ((u16x4*)z)[i4] = o4;
}

__global__ __launch_bounds__(256)
void gather_k(const int* __restrict__ x, const float* __restrict__ emb, float* __restrict__ h)
{
  const long long tok = blockIdx.x;
  const long long r = (long long)x[tok] << 8;
  ((f32x4*)h)[(tok << 8) + threadIdx.x] = ((const f32x4*)emb)[r + threadIdx.x];
}

// f32 [R][C] -> bf16 [C][R]
__global__ __launch_bounds__(256)
void tcast_k(const float* __restrict__ in, u16* __restrict__ out, int R, int C)
{
  __shared__ float tile[32][33];
  const int tx = threadIdx.x & 31, ty = threadIdx.x >> 5;
  const long long r0 = (long long)blockIdx.y << 5, c0 = (long long)blockIdx.x << 5;
#pragma unroll
  for (int yy = 0; yy < 32; yy += 8)
    tile[ty + yy][tx] = in[(r0 + ty + yy) * C + c0 + tx];
  __syncthreads();
#pragma unroll
  for (int yy = 0; yy < 32; yy += 8)
    out[(c0 + ty + yy) * R + r0 + tx] = f2bf(tile[tx][ty + yy]);
}

__global__ __launch_bounds__(256)
void wqkv_k(const float* __restrict__ Wq, const float* __restrict__ Wk,
            const float* __restrict__ Wv, u16* __restrict__ o)
{
  const int n = blockIdx.y;
  const long long e = (long long)blockIdx.x * 256 + threadIdx.x;
  float v = 0.f;
  if (n < 64)       v = Wq[e * 64 + n];
  else if (n < 128) v = Wk[e * 64 + (n - 64)];
  else if (n < 192) v = Wv[e * 64 + (n - 128)];
  o[(long long)n * 1024 + e] = f2bf(v);
}

__global__ __launch_bounds__(256)
void bqkv_k(const float* __restrict__ bq, const float* __restrict__ bk,
            const float* __restrict__ bv, float* __restrict__ o)
{
  const int n = threadIdx.x;
  float v = 0.f;
  if (n < 64)       v = bq[n];
  else if (n < 128) v = bk[n - 64];
  else if (n < 192) v = bv[n - 128];
  o[n] = v;
}

__global__ __launch_bounds__(256)
void wdsum_k(const float* __restrict__ Wd, u16* __restrict__ o)
{
  const int i = blockIdx.x * 256 + threadIdx.x;
  const int a = i & 63, e = i >> 6;
  float s = 0.f;
#pragma unroll
  for (int hh = 0; hh < 16; ++hh) s += Wd[(long long)(hh * 64 + a) * 1024 + e];
  o[i] = f2bf(s);
}

// qkv = bf16(p0+p1+bqkv), plus vT scatter for v-cols [128,192) -> vT[b*64+a][2048]
__global__ __launch_bounds__(256)
void reduce_qkv(const float* __restrict__ p, const float* __restrict__ bqkv,
                u16* __restrict__ qkv, u16* __restrict__ vT)
{
  const long long i4 = (long long)blockIdx.x * 256 + threadIdx.x;
  const int c4 = (int)(i4 & 63);
  const long long row = i4 >> 6;
  f32x4 s = ((const f32x4*)p)[i4] + ((const f32x4*)p)[i4 + 262144]
          + ((const f32x4*)bqkv)[c4];
  u16x4 o;
#pragma unroll
  for (int e = 0; e < 4; ++e) o[e] = f2bf(s[e]);
  ((u16x4*)qkv)[i4] = o;
  if (c4 >= 32 && c4 < 48) {
    const long long b = row >> 11, sidx = row & 2047;
#pragma unroll
    for (int e = 0; e < 4; ++e) {
      const int a = (c4 - 32) * 4 + e;
      vT[(b * 64 + a) * 2048 + sidx] = o[e];
    }
  }
}

extern "C" void kernel_launch(void* const* d_in, const int* in_sizes, int n_in,
                              void* d_out, int out_size, void* d_ws, size_t ws_size,
                              hipStream_t stream) {
  const int*   x   = (const int*)d_in[0];
  const float* emb = (const float*)d_in[1];
  const float* Wq  = (const float*)d_in[2];
  const float* bq  = (const float*)d_in[3];
  const float* Wk  = (const float*)d_in[4];
  const float* bk  = (const float*)d_in[5];
  const float* Wv  = (const float*)d_in[6];
  const float* bv  = (const float*)d_in[7];
  const float* Wd  = (const float*)d_in[8];
  const float* bd  = (const float*)d_in[9];
  const float* g1  = (const float*)d_in[10];
  const float* be1 = (const float*)d_in[11];
  const float* g2  = (const float*)d_in[12];
  const float* be2 = (const float*)d_in[13];
  const float* W1  = (const float*)d_in[14];
  const float* c1  = (const float*)d_in[15];
  const float* W2  = (const float*)d_in[16];
  const float* c2  = (const float*)d_in[17];
  const float* Wfc = (const float*)d_in[18];
  const float* bfc = (const float*)d_in[19];
  float* out = (float*)d_out;

  hipFuncSetAttribute(reinterpret_cast<const void*>(gemm8p<0>),
                      hipFuncAttributeMaxDynamicSharedMemorySize, 131072);
  hipFuncSetAttribute(reinterpret_cast<const void*>(gemm8p<2>),
                      hipFuncAttributeMaxDynamicSharedMemorySize, 131072);
  hipFuncSetAttribute(reinterpret_cast<const void*>(gemm8p<3>),
                      hipFuncAttributeMaxDynamicSharedMemorySize, 131072);

  char* ws = (char*)d_ws;
  size_t off = 0;
  auto alloc = [&](size_t bytes) { void* p = ws + off; off = (off + bytes + 255) & ~(size_t)255; return p; };
  float*  h     = (float*) alloc(4096ull * 1024 * 4);
  u16*    z     = (u16*)   alloc(4096ull * 1024 * 2);
  u16*    qkv   = (u16*)   alloc(4096ull * 256 * 2);
  u16*    vT    = (u16*)   alloc(2ull * 64 * 2048 * 2);
  u16*    head  = (u16*)   alloc(4096ull * 64 * 2);
  u16*    mid   = (u16*)   alloc(4096ull * 4096 * 2);
  // SCR aliasing (lifetimes disjoint): partQ [QKV->reduce] ; {po,pm,pls}
  // [flashp->fmerge] ; partF [FFN2->reduce_ln]
  char*   SCR   = (char*)  alloc(2ull * 4096 * 1024 * 4);
  float*  partQ = (float*)SCR;
  float*  po    = (float*)SCR;
  float*  pm    = (float*)(SCR + 4194304);
  float*  pls   = (float*)(SCR + 4194304 + 65536);
  u16*    partF = (u16*)SCR;
  u16*    Wqkvt = (u16*)   alloc(256ull * 1024 * 2);
  float*  bqkv  = (float*) alloc(256 * 4);
  u16*    Wdst  = (u16*)   alloc(1024ull * 64 * 2);
  u16*    W1t   = (u16*)   alloc(4096ull * 1024 * 2);
  u16*    W2t   = (u16*)   alloc(1024ull * 4096 * 2);
  u16*    Wfct  = (u16*)   alloc(32000ull * 1024 * 2);

  // ---- prep (every launch; no caching allowed) ----
  gather_k<<<4096, 256, 0, stream>>>(x, emb, h);
  wqkv_k<<<dim3(4, 256), 256, 0, stream>>>(Wq, Wk, Wv, Wqkvt);
  bqkv_k<<<1, 256, 0, stream>>>(bq, bk, bv, bqkv);
  wdsum_k<<<256, 256, 0, stream>>>(Wd, Wdst);
  tcast_k<<<dim3(128, 32), 256, 0, stream>>>(W1, W1t, 1024, 4096);
  tcast_k<<<dim3(32, 128), 256, 0, stream>>>(W2, W2t, 4096, 1024);
  tcast_k<<<dim3(1000, 32), 256, 0, stream>>>(Wfc, Wfct, 1024, 32000);

  for (int layer = 0; layer < 8; ++layer) {
    if (layer == 0)
      ln_k<<<4096, 256, 0, stream>>>(h, g1, be1, z);
    gemm_bt<0><<<dim3(64, 1, 2), 256, 0, stream>>>(z, Wqkvt, partQ, nullptr, nullptr, 1.f,
        512, 1024, 1024, 256, 32, 32, 2, 0, 0, 1048576);
    reduce_qkv<<<1024, 256, 0, stream>>>(partQ, bqkv, qkv, vT);
    // fused attention, split-KV x4 + LSE merge
    flashp_k<<<1024, 64, 0, stream>>>(qkv, vT, po, pm, pls);
    fmerge_k<<<256, 64, 0, stream>>>(po, pm, pls, head);
    gemm_bt<1><<<dim3(256, 1, 1), 256, 0, stream>>>(head, Wdst, h, nullptr, bd, 1.f,
        64, 64, 64, 1024, 32, 32, 1, 0, 0, 0);
    ln_k<<<4096, 256, 0, stream>>>(h, g2, be2, z);
    // mid = relu(z2 @ W1 + c1) -- R5 engine
    gemm8p<3><<<dim3(256, 1, 1), 512, 131072, stream>>>(z, W1t, nullptr, mid, c1, 1.f,
        1024, 1024, 1024, 4096, 16, 16, 1, 0, 0, 0);
    // partF[sp] = bf16(mid @ W2^T) (split-K x4, K=1024 each) -- R5 engine
    gemm8p<2><<<dim3(64, 1, 4), 512, 131072, stream>>>(mid, W2t, nullptr, partF, nullptr, 1.f,
        1024, 4096, 4096, 1024, 16, 16, 4, 0, 0, 4194304);
    if (layer < 7)
      reduce_ln_k<0><<<4096, 256, 0, stream>>>(partF, h, c2, g1, be1, z);
    else
      reduce_ln_k<1><<<4096, 256, 0, stream>>>(partF, h, c2, nullptr, nullptr, z);
  }
  // out = hb @ Wfc + bfc -- R5 engine, grouped gm=8
  gemm8p<0><<<dim3(2000, 1, 1), 512, 131072, stream>>>(z, Wfct, out, nullptr, bfc, 1.f,
      1024, 1024, 1024, 32000, 16, 8, 1, 0, 0, 0);
}

// Round 9
// 1788.442 us; speedup vs baseline: 1.0926x; 1.0102x over previous
//
#include <hip/hip_runtime.h>

typedef unsigned short u16;
typedef __attribute__((ext_vector_type(4))) float f32x4;
typedef __attribute__((ext_vector_type(8))) __bf16 bf16x8;
typedef __attribute__((ext_vector_type(4))) unsigned short u16x4;

static __device__ __forceinline__ u16 f2bf(float f) {
  union { float f; unsigned u; } v; v.f = f;
  unsigned r = v.u + 0x7fffu + ((v.u >> 16) & 1u);
  return (u16)(r >> 16);
}

#define GLD_LDS(g, l) __builtin_amdgcn_global_load_lds( \
    (const __attribute__((address_space(1))) void*)(g), \
    (__attribute__((address_space(3))) void*)(l), 16, 0, 0)

// ---------------------------------------------------------------------------
// 256x256 BK=64 8-wave GEMM, m201-style 4-phase/K-tile schedule.
// NO sched_barrier(0) anywhere (m141: order-pinning regresses); raw s_barrier
// + asm lgkmcnt only. One half-tile staged per phase; vmcnt(4) once/K-tile.
// T2 swizzle: data(row, slot8) at slot8^(row&7); pre-swizzled global source,
// swizzled ds_read, linear gload_lds dest (rule #21).
// EPI: 0 = Cf = alpha*acc + bias; 2 = Cb = bf16(acc+bias); 3 = bf16 relu.
// ---------------------------------------------------------------------------
template<int EPI>
__global__ __launch_bounds__(512, 2)
void gemm8p(const u16* __restrict__ A, const u16* __restrict__ B,
            float* __restrict__ Cf, u16* __restrict__ Cb,
            const float* __restrict__ bias, float alpha,
            int K, int lda, int ldb, int ldc, int mtiles, int gm, int nsplit,
            long long sA, long long sB, long long sC)
{
  extern __shared__ u16 lds8[];
  const int t = threadIdx.x;
  const int w = t >> 6, l = t & 63;
  const int l15 = l & 15, l16 = l >> 4;
  const int wr = w >> 2, wc = w & 3;

  int wg = blockIdx.x;
  const int nwg = gridDim.x;
  {
    const int q = nwg >> 3, r = nwg & 7;
    const int xcd = wg & 7, loc = wg >> 3;
    wg = (xcd < r ? xcd * (q + 1) : r * (q + 1) + (xcd - r) * q) + loc;
  }
  const int ntiles = nwg / mtiles;
  const int gsz = gm * ntiles;
  const int gi = wg / gsz;
  const int rr = wg - gi * gsz;
  const int nt = rr / gm;
  const int mt = gi * gm + (rr - nt * gm);
  const int m0 = mt << 8, n0 = nt << 8;

  const int bz = blockIdx.z;
  int batch = bz, sp = 0;
  if (nsplit > 1) { batch = bz / nsplit; sp = bz - batch * nsplit; }
  const u16* Ab = A + (long long)batch * sA + (long long)sp * K;
  const u16* Bb = B + (long long)batch * sB + (long long)sp * K;
  const long long cbase = (long long)bz * sC;

  // staging: per half-tile (128 rows x 64 cols), 2 gload_lds/thread.
  // unit u = j*512 + w*64 + l covers row u>>3, dest slot u&7, src slot
  // (u&7)^(row&7). LDS halves: A at (buf*2+h)*8192, B at +32768.
  int srow[2], scol[2], sdst[2];
#pragma unroll
  for (int j = 0; j < 2; ++j) {
    const int u = (j << 9) + (w << 6) + l;
    srow[j] = u >> 3;
    scol[j] = ((u & 7) ^ ((u >> 3) & 7)) << 3;
    sdst[j] = ((j << 9) + (w << 6)) << 3;
  }
  auto STAGE_A = [&](int buf, int h, int ktgt) {
#pragma unroll
    for (int j = 0; j < 2; ++j)
      GLD_LDS(Ab + (long long)(m0 + h * 128 + srow[j]) * lda + ktgt * 64 + scol[j],
              &lds8[(buf * 2 + h) * 8192 + sdst[j]]);
  };
  auto STAGE_B = [&](int buf, int h, int ktgt) {
#pragma unroll
    for (int j = 0; j < 2; ++j)
      GLD_LDS(Bb + (long long)(n0 + h * 128 + srow[j]) * ldb + ktgt * 64 + scol[j],
              &lds8[32768 + (buf * 2 + h) * 8192 + sdst[j]]);
  };

  bf16x8 aF[4][2], bF0[2][2], bF1[2][2];
  f32x4 acc[8][4] = {};

  // wave reads: A half = wr (rows wr*128..+127), quarters via mbase;
  // B half = wc>>1, rows (wc&1)*64 + nbase*16 .. (+2 frags).
  auto RDA = [&](int buf, int mbase) {
#pragma unroll
    for (int mf = 0; mf < 4; ++mf) {
      const int r2 = (mbase + mf) * 16 + l15;
#pragma unroll
      for (int kk = 0; kk < 2; ++kk)
        aF[mf][kk] = *(const bf16x8*)&lds8[(buf * 2 + wr) * 8192 + r2 * 64 +
                                           (((kk << 2) + l16) ^ (r2 & 7)) * 8];
    }
  };
  auto RDB = [&](bf16x8 (&dst)[2][2], int buf, int nbase) {
#pragma unroll
    for (int nf = 0; nf < 2; ++nf) {
      const int r2 = (wc & 1) * 64 + (nbase + nf) * 16 + l15;
#pragma unroll
      for (int kk = 0; kk < 2; ++kk)
        dst[nf][kk] = *(const bf16x8*)&lds8[32768 + (buf * 2 + (wc >> 1)) * 8192 + r2 * 64 +
                                            (((kk << 2) + l16) ^ (r2 & 7)) * 8];
    }
  };

#define MM16(MB, NB, BF) \
  do { \
    __builtin_amdgcn_s_setprio(1); \
    _Pragma("unroll") \
    for (int mf = 0; mf < 4; ++mf) \
      _Pragma("unroll") \
      for (int nf = 0; nf < 2; ++nf) \
        _Pragma("unroll") \
        for (int kk = 0; kk < 2; ++kk) \
          acc[MB + mf][NB + nf] = __builtin_amdgcn_mfma_f32_16x16x32_bf16( \
              aF[mf][kk], BF[nf][kk], acc[MB + mf][NB + nf], 0, 0, 0); \
    __builtin_amdgcn_s_setprio(0); \
  } while (0)

  const int nkt = K >> 6;

  // prologue: kt0 fully + kt1 B-halves; vmcnt(4) -> kt0 landed
  STAGE_B(0, 0, 0); STAGE_B(0, 1, 0);
  STAGE_A(0, 0, 0); STAGE_A(0, 1, 0);
  if (1 < nkt) { STAGE_B(1, 0, 1); STAGE_B(1, 1, 1); }
  asm volatile("s_waitcnt vmcnt(4)" ::: "memory");
  __builtin_amdgcn_s_barrier();

  for (int kt = 0; kt < nkt; ++kt) {
    const int buf = kt & 1, nb = buf ^ 1;
    // ---- ph1: A-low quarters + B-first; stage A0(kt+1) ----
    RDA(buf, 0);
    RDB(bF0, buf, 0);
    if (kt + 1 < nkt) STAGE_A(nb, 0, kt + 1);
    asm volatile("s_waitcnt lgkmcnt(8)" ::: "memory");
    __builtin_amdgcn_s_barrier();
    asm volatile("s_waitcnt lgkmcnt(0)" ::: "memory");
    MM16(0, 0, bF0);
    __builtin_amdgcn_s_barrier();
    // ---- ph2: B-second; stage A1(kt+1) ----
    RDB(bF1, buf, 2);
    if (kt + 1 < nkt) STAGE_A(nb, 1, kt + 1);
    __builtin_amdgcn_s_barrier();
    asm volatile("s_waitcnt lgkmcnt(0)" ::: "memory");
    MM16(0, 2, bF1);
    __builtin_amdgcn_s_barrier();
    // ---- ph3: A-high quarters; stage B0(kt+2) ----
    RDA(buf, 4);
    if (kt + 2 < nkt) STAGE_B(buf, 0, kt + 2);
    __builtin_amdgcn_s_barrier();
    asm volatile("s_waitcnt lgkmcnt(0)" ::: "memory");
    MM16(4, 0, bF0);
    __builtin_amdgcn_s_barrier();
    // ---- ph4: stage B1(kt+2); counted vmcnt ----
    if (kt + 2 < nkt) STAGE_B(buf, 1, kt + 2);
    if (kt + 1 < nkt) {
      if (kt + 2 < nkt) asm volatile("s_waitcnt vmcnt(4)" ::: "memory");
      else              asm volatile("s_waitcnt vmcnt(0)" ::: "memory");
    }
    __builtin_amdgcn_s_barrier();
    MM16(4, 2, bF1);
    __builtin_amdgcn_s_barrier();
  }
#undef MM16

#pragma unroll
  for (int mf = 0; mf < 8; ++mf) {
    const int rbase = m0 + wr * 128 + mf * 16 + l16 * 4;
#pragma unroll
    for (int nf = 0; nf < 4; ++nf) {
      const int col = n0 + wc * 64 + nf * 16 + l15;
      const float bv = bias ? bias[col] : 0.f;
#pragma unroll
      for (int r = 0; r < 4; ++r) {
        const long long idx = cbase + (long long)(rbase + r) * ldc + col;
        const float v = acc[mf][nf][r];
        if (EPI == 0)      Cf[idx] = alpha * v + bv;
        else if (EPI == 2) Cb[idx] = f2bf(v + bv);
        else               { float x = v + bv; Cb[idx] = f2bf(x > 0.f ? x : 0.f); }
      }
    }
  }
}

// ---- legacy 128x128 engine (small shapes: QKV, headWd) ----
template<int EPI>
__global__ __launch_bounds__(256)
void gemm_bt(const u16* __restrict__ A, const u16* __restrict__ B,
             float* __restrict__ Cf, u16* __restrict__ Cb,
             const float* __restrict__ bias, float alpha,
             int K, int lda, int ldb, int ldc, int mtiles, int gm, int nsplit,
             long long sA, long long sB, long long sC)
{
  __shared__ u16 ldsA[128 * 32];
  __shared__ u16 ldsB[128 * 32];
  const int t = threadIdx.x;
  const int w = t >> 6, l = t & 63;

  int wg = blockIdx.x;
  const int nwg = gridDim.x;
  {
    const int q = nwg >> 3, r = nwg & 7;
    const int xcd = wg & 7, loc = wg >> 3;
    wg = (xcd < r ? xcd * (q + 1) : r * (q + 1) + (xcd - r) * q) + loc;
  }
  const int ntiles = nwg / mtiles;
  const int gsz = gm * ntiles;
  const int gi = wg / gsz;
  const int rr = wg - gi * gsz;
  const int nt = rr / gm;
  const int mt = gi * gm + (rr - nt * gm);
  const int m0 = mt << 7, n0 = nt << 7;

  const int bzRaw = blockIdx.z;
  int batch = bzRaw, sp = 0;
  if (nsplit > 1) { batch = bzRaw / nsplit; sp = bzRaw - batch * nsplit; }
  const u16* Ab = A + (long long)batch * sA + (long long)sp * K;
  const u16* Bb = B + (long long)batch * sB + (long long)sp * K;
  const long long cbase = (long long)bzRaw * sC;

  const int wr = (w >> 1) << 6, wc = (w & 1) << 6;
  const int l15 = l & 15, l16 = l >> 4;
  f32x4 acc[4][4] = {};

  for (int k0 = 0; k0 < K; k0 += 32) {
#pragma unroll
    for (int r = 0; r < 2; ++r) {
      const int o = (r << 12) + (t << 4);
      const int row = o >> 6;
      const int cole = (o & 63) >> 1;
      GLD_LDS(Ab + (long long)(m0 + row) * lda + k0 + cole, &ldsA[(r << 11) + (w << 9)]);
      GLD_LDS(Bb + (long long)(n0 + row) * ldb + k0 + cole, &ldsB[(r << 11) + (w << 9)]);
    }
    __syncthreads();
    bf16x8 af[4], bg[4];
#pragma unroll
    for (int i = 0; i < 4; ++i) {
      af[i] = *(const bf16x8*)&ldsA[(wr + i * 16 + l15) * 32 + l16 * 8];
      bg[i] = *(const bf16x8*)&ldsB[(wc + i * 16 + l15) * 32 + l16 * 8];
    }
#pragma unroll
    for (int i = 0; i < 4; ++i)
#pragma unroll
      for (int j = 0; j < 4; ++j)
        acc[i][j] = __builtin_amdgcn_mfma_f32_16x16x32_bf16(af[i], bg[j], acc[i][j], 0, 0, 0);
    __syncthreads();
  }

#pragma unroll
  for (int i = 0; i < 4; ++i) {
    const int rbase = m0 + wr + i * 16 + l16 * 4;
#pragma unroll
    for (int j = 0; j < 4; ++j) {
      const int col = n0 + wc + j * 16 + l15;
      const float bv = bias ? bias[col] : 0.f;
#pragma unroll
      for (int r = 0; r < 4; ++r) {
        const long long idx = cbase + (long long)(rbase + r) * ldc + col;
        const float v = acc[i][j][r];
        if (EPI == 0)      Cf[idx] = alpha * v + bv;
        else if (EPI == 1) Cf[idx] += v + bv;
        else if (EPI == 2) Cb[idx] = f2bf(v + bv);
        else               { float x = v + bv; Cb[idx] = f2bf(x > 0.f ? x : 0.f); }
      }
    }
  }
}

// ---------------- fused flash attention (R5 form: 1 wave / 16 q-rows) -------
__device__ __forceinline__ void fstep(
    const bf16x8 (&ck)[4][2], const bf16x8 (&cv)[4][2],
    bf16x8 (&nk)[4][2], bf16x8 (&nv)[4][2],
    const bf16x8 (&qf)[2], float (&m)[4], float (&ls)[4], f32x4 (&o)[4],
    const u16* qb, const u16* vb, int kvn, u16* pl, int l15, int l16)
{
  f32x4 s[4] = {};
#pragma unroll
  for (int ni = 0; ni < 4; ++ni)
#pragma unroll
    for (int kk = 0; kk < 2; ++kk)
      s[ni] = __builtin_amdgcn_mfma_f32_16x16x32_bf16(qf[kk], ck[ni][kk], s[ni], 0, 0, 0);
#pragma unroll
  for (int ni = 0; ni < 4; ++ni)
#pragma unroll
    for (int kk = 0; kk < 2; ++kk)
      nk[ni][kk] = *(const bf16x8*)(qb + (kvn + ni * 16 + l15) * 256 + 64 + kk * 32 + l16 * 8);
#pragma unroll
  for (int ni = 0; ni < 4; ++ni) s[ni] *= 0.125f;
  float al[4], ps[4];
#pragma unroll
  for (int r = 0; r < 4; ++r) {
    float v = fmaxf(fmaxf(s[0][r], s[1][r]), fmaxf(s[2][r], s[3][r]));
    v = fmaxf(v, __shfl_xor(v, 1)); v = fmaxf(v, __shfl_xor(v, 2));
    v = fmaxf(v, __shfl_xor(v, 4)); v = fmaxf(v, __shfl_xor(v, 8));
    const float mn = fmaxf(m[r], v);
    al[r] = __expf(m[r] - mn);
    m[r] = mn;
    ps[r] = 0.f;
  }
#pragma unroll
  for (int ni = 0; ni < 4; ++ni)
#pragma unroll
    for (int r = 0; r < 4; ++r) {
      const float p = __expf(s[ni][r] - m[r]);
      ps[r] += p;
      pl[(l16 * 4 + r) * 72 + ni * 16 + l15] = f2bf(p);
    }
#pragma unroll
  for (int r = 0; r < 4; ++r) {
    float t = ps[r];
    t += __shfl_xor(t, 1); t += __shfl_xor(t, 2);
    t += __shfl_xor(t, 4); t += __shfl_xor(t, 8);
    ls[r] = ls[r] * al[r] + t;
  }
#pragma unroll
  for (int nd = 0; nd < 4; ++nd)
#pragma unroll
    for (int r = 0; r < 4; ++r) o[nd][r] *= al[r];
  bf16x8 pa[2];
#pragma unroll
  for (int kk = 0; kk < 2; ++kk)
    pa[kk] = *(const bf16x8*)&pl[l15 * 72 + kk * 32 + l16 * 8];
#pragma unroll
  for (int nd = 0; nd < 4; ++nd)
#pragma unroll
    for (int kk = 0; kk < 2; ++kk)
      o[nd] = __builtin_amdgcn_mfma_f32_16x16x32_bf16(pa[kk], cv[nd][kk], o[nd], 0, 0, 0);
#pragma unroll
  for (int nd = 0; nd < 4; ++nd)
#pragma unroll
    for (int kk = 0; kk < 2; ++kk)
      nv[nd][kk] = *(const bf16x8*)(vb + (nd * 16 + l15) * 2048 + kvn + kk * 32 + l16 * 8);
}

__global__ __launch_bounds__(64)
void flash_k(const u16* __restrict__ qkv, const u16* __restrict__ vT,
             u16* __restrict__ head)
{
  __shared__ u16 pl[16 * 72];
  const int l = threadIdx.x, l15 = l & 15, l16 = l >> 4;
  const int b = blockIdx.x >> 7, q0 = (blockIdx.x & 127) << 4;
  const u16* qb = qkv + (long long)b * 2048 * 256;
  const u16* vb = vT + (long long)b * 64 * 2048;
  bf16x8 qf[2];
#pragma unroll
  for (int kk = 0; kk < 2; ++kk)
    qf[kk] = *(const bf16x8*)(qb + (q0 + l15) * 256 + kk * 32 + l16 * 8);
  float m[4], ls[4];
  f32x4 o[4] = {};
#pragma unroll
  for (int r = 0; r < 4; ++r) { m[r] = -1e30f; ls[r] = 0.f; }
  bf16x8 ka[4][2], va[4][2], kb[4][2], vb2[4][2];
#pragma unroll
  for (int ni = 0; ni < 4; ++ni)
#pragma unroll
    for (int kk = 0; kk < 2; ++kk) {
      ka[ni][kk] = *(const bf16x8*)(qb + (ni * 16 + l15) * 256 + 64 + kk * 32 + l16 * 8);
      va[ni][kk] = *(const bf16x8*)(vb + (ni * 16 + l15) * 2048 + kk * 32 + l16 * 8);
    }
  for (int t = 0; t < 32; t += 2) {
    fstep(ka, va, kb, vb2, qf, m, ls, o, qb, vb, (t + 1) * 64, pl, l15, l16);
    fstep(kb, vb2, ka, va, qf, m, ls, o, qb, vb,
          (t + 2 < 32 ? (t + 2) * 64 : 31 * 64), pl, l15, l16);
  }
#pragma unroll
  for (int nd = 0; nd < 4; ++nd)
#pragma unroll
    for (int r = 0; r < 4; ++r)
      head[((long long)b * 2048 + q0 + l16 * 4 + r) * 64 + nd * 16 + l15] =
          f2bf(o[nd][r] / ls[r]);
}

// LayerNorm over rows of 1024 f32 -> bf16 out
__global__ __launch_bounds__(256)
void ln_k(const float* __restrict__ x, const float* __restrict__ g,
          const float* __restrict__ b, u16* __restrict__ z)
{
  const long long row = blockIdx.x;
  f32x4 v = ((const f32x4*)(x + row * 1024))[threadIdx.x];
  float s = v[0] + v[1] + v[2] + v[3];
  float q = v[0] * v[0] + v[1] * v[1] + v[2] * v[2] + v[3] * v[3];
#pragma unroll
  for (int o = 32; o; o >>= 1) { s += __shfl_down(s, o); q += __shfl_down(q, o); }
  __shared__ float rs_[4], rq_[4];
  const int l = threadIdx.x & 63, w = threadIdx.x >> 6;
  if (l == 0) { rs_[w] = s; rq_[w] = q; }
  __syncthreads();
  s = rs_[0] + rs_[1] + rs_[2] + rs_[3];
  q = rq_[0] + rq_[1] + rq_[2] + rq_[3];
  const float mu = s * (1.f / 1024.f);
  const float rstd = rsqrtf(q * (1.f / 1024.f) - mu * mu + 1e-5f);
  const f32x4 gv = ((const f32x4*)g)[threadIdx.x];
  const f32x4 bv = ((const f32x4*)b)[threadIdx.x];
  u16x4 o4;
#pragma unroll
  for (int e = 0; e < 4; ++e) o4[e] = f2bf((v[e] - mu) * rstd * gv[e] + bv[e]);
  ((u16x4*)(z + row * 1024))[threadIdx.x] = o4;
}

// fused: hnew = h + sum_{s<4} bf16partial_s + c2 ; MODE0: h=hnew, z=LN(hnew);
// MODE1: z=bf16(hnew) (h dead)
template<int MODE>
__global__ __launch_bounds__(256)
void reduce_ln_k(const u16* __restrict__ p, float* __restrict__ h,
                 const float* __restrict__ c2, const float* __restrict__ g,
                 const float* __restrict__ b, u16* __restrict__ z)
{
  const long long row = blockIdx.x;
  const int t = threadIdx.x;
  const long long i4 = (row << 8) + t;
  f32x4 v = ((const f32x4*)h)[i4] + ((const f32x4*)c2)[t];
#pragma unroll
  for (int s = 0; s < 4; ++s) {
    u16x4 pv = ((const u16x4*)p)[i4 + (long long)s * 1048576];
#pragma unroll
    for (int e = 0; e < 4; ++e) {
      union { unsigned u; float f; } x; x.u = ((unsigned)pv[e]) << 16;
      v[e] += x.f;
    }
  }
  u16x4 o4;
  if (MODE == 1) {
#pragma unroll
    for (int e = 0; e < 4; ++e) o4[e] = f2bf(v[e]);
  } else {
    ((f32x4*)h)[i4] = v;
    float s = v[0] + v[1] + v[2] + v[3];
    float q = v[0] * v[0] + v[1] * v[1] + v[2] * v[2] + v[3] * v[3];
#pragma unroll
    for (int o = 32; o; o >>= 1) { s += __shfl_down(s, o); q += __shfl_down(q, o); }
    __shared__ float rs_[4], rq_[4];
    const int l = t & 63, w = t >> 6;
    if (l == 0) { rs_[w] = s; rq_[w] = q; }
    __syncthreads();
    s = rs_[0] + rs_[1] + rs_[2] + rs_[3];
    q = rq_[0] + rq_[1] + rq_[2] + rq_[3];
    const float mu = s * (1.f / 1024.f);
    const float rstd = rsqrtf(q * (1.f / 1024.f) - mu * mu + 1e-5f);
    const f32x4 gv = ((const f32x4*)g)[t];
    const f32x4 bv = ((const f32x4*)b)[t];
#pragma unroll
    for (int e = 0; e < 4; ++e) o4[e] = f2bf((v[e] - mu) * rstd * gv[e] + bv[e]);
  }
  ((u16x4*)z)[i4] = o4;
}

__global__ __launch_bounds__(256)
void gather_k(const int* __restrict__ x, const float* __restrict__ emb, float* __restrict__ h)
{
  const long long tok = blockIdx.x;
  const long long r = (long long)x[tok] << 8;
  ((f32x4*)h)[(tok << 8) + threadIdx.x] = ((const f32x4*)emb)[r + threadIdx.x];
}

// f32 [R][C] -> bf16 [C][R]
__global__ __launch_bounds__(256)
void tcast_k(const float* __restrict__ in, u16* __restrict__ out, int R, int C)
{
  __shared__ float tile[32][33];
  const int tx = threadIdx.x & 31, ty = threadIdx.x >> 5;
  const long long r0 = (long long)blockIdx.y << 5, c0 = (long long)blockIdx.x << 5;
#pragma unroll
  for (int yy = 0; yy < 32; yy += 8)
    tile[ty + yy][tx] = in[(r0 + ty + yy) * C + c0 + tx];
  __syncthreads();
#pragma unroll
  for (int yy = 0; yy < 32; yy += 8)
    out[(c0 + ty + yy) * R + r0 + tx] = f2bf(tile[tx][ty + yy]);
}

__global__ __launch_bounds__(256)
void wqkv_k(const float* __restrict__ Wq, const float* __restrict__ Wk,
            const float* __restrict__ Wv, u16* __restrict__ o)
{
  const int n = blockIdx.y;
  const long long e = (long long)blockIdx.x * 256 + threadIdx.x;
  float v = 0.f;
  if (n < 64)       v = Wq[e * 64 + n];
  else if (n < 128) v = Wk[e * 64 + (n - 64)];
  else if (n < 192) v = Wv[e * 64 + (n - 128)];
  o[(long long)n * 1024 + e] = f2bf(v);
}

__global__ __launch_bounds__(256)
void bqkv_k(const float* __restrict__ bq, const float* __restrict__ bk,
            const float* __restrict__ bv, float* __restrict__ o)
{
  const int n = threadIdx.x;
  float v = 0.f;
  if (n < 64)       v = bq[n];
  else if (n < 128) v = bk[n - 64];
  else if (n < 192) v = bv[n - 128];
  o[n] = v;
}

__global__ __launch_bounds__(256)
void wdsum_k(const float* __restrict__ Wd, u16* __restrict__ o)
{
  const int i = blockIdx.x * 256 + threadIdx.x;
  const int a = i & 63, e = i >> 6;
  float s = 0.f;
#pragma unroll
  for (int hh = 0; hh < 16; ++hh) s += Wd[(long long)(hh * 64 + a) * 1024 + e];
  o[i] = f2bf(s);
}

// qkv = bf16(p0+p1+bqkv), plus vT scatter for v-cols [128,192) -> vT[b*64+a][2048]
__global__ __launch_bounds__(256)
void reduce_qkv(const float* __restrict__ p, const float* __restrict__ bqkv,
                u16* __restrict__ qkv, u16* __restrict__ vT)
{
  const long long i4 = (long long)blockIdx.x * 256 + threadIdx.x;
  const int c4 = (int)(i4 & 63);
  const long long row = i4 >> 6;
  f32x4 s = ((const f32x4*)p)[i4] + ((const f32x4*)p)[i4 + 262144]
          + ((const f32x4*)bqkv)[c4];
  u16x4 o;
#pragma unroll
  for (int e = 0; e < 4; ++e) o[e] = f2bf(s[e]);
  ((u16x4*)qkv)[i4] = o;
  if (c4 >= 32 && c4 < 48) {
    const long long b = row >> 11, sidx = row & 2047;
#pragma unroll
    for (int e = 0; e < 4; ++e) {
      const int a = (c4 - 32) * 4 + e;
      vT[(b * 64 + a) * 2048 + sidx] = o[e];
    }
  }
}

extern "C" void kernel_launch(void* const* d_in, const int* in_sizes, int n_in,
                              void* d_out, int out_size, void* d_ws, size_t ws_size,
                              hipStream_t stream) {
  const int*   x   = (const int*)d_in[0];
  const float* emb = (const float*)d_in[1];
  const float* Wq  = (const float*)d_in[2];
  const float* bq  = (const float*)d_in[3];
  const float* Wk  = (const float*)d_in[4];
  const float* bk  = (const float*)d_in[5];
  const float* Wv  = (const float*)d_in[6];
  const float* bv  = (const float*)d_in[7];
  const float* Wd  = (const float*)d_in[8];
  const float* bd  = (const float*)d_in[9];
  const float* g1  = (const float*)d_in[10];
  const float* be1 = (const float*)d_in[11];
  const float* g2  = (const float*)d_in[12];
  const float* be2 = (const float*)d_in[13];
  const float* W1  = (const float*)d_in[14];
  const float* c1  = (const float*)d_in[15];
  const float* W2  = (const float*)d_in[16];
  const float* c2  = (const float*)d_in[17];
  const float* Wfc = (const float*)d_in[18];
  const float* bfc = (const float*)d_in[19];
  float* out = (float*)d_out;

  hipFuncSetAttribute(reinterpret_cast<const void*>(gemm8p<0>),
                      hipFuncAttributeMaxDynamicSharedMemorySize, 131072);
  hipFuncSetAttribute(reinterpret_cast<const void*>(gemm8p<2>),
                      hipFuncAttributeMaxDynamicSharedMemorySize, 131072);
  hipFuncSetAttribute(reinterpret_cast<const void*>(gemm8p<3>),
                      hipFuncAttributeMaxDynamicSharedMemorySize, 131072);

  char* ws = (char*)d_ws;
  size_t off = 0;
  auto alloc = [&](size_t bytes) { void* p = ws + off; off = (off + bytes + 255) & ~(size_t)255; return p; };
  float*  h     = (float*) alloc(4096ull * 1024 * 4);
  u16*    z     = (u16*)   alloc(4096ull * 1024 * 2);
  u16*    qkv   = (u16*)   alloc(4096ull * 256 * 2);
  u16*    vT    = (u16*)   alloc(2ull * 64 * 2048 * 2);
  u16*    head  = (u16*)   alloc(4096ull * 64 * 2);
  u16*    mid   = (u16*)   alloc(4096ull * 4096 * 2);
  // SCR aliasing (lifetimes disjoint): partQ [QKV->reduce]; partF [FFN2->reduce_ln]
  char*   SCR   = (char*)  alloc(2ull * 4096 * 1024 * 4);
  float*  partQ = (float*)SCR;
  u16*    partF = (u16*)SCR;
  u16*    Wqkvt = (u16*)   alloc(256ull * 1024 * 2);
  float*  bqkv  = (float*) alloc(256 * 4);
  u16*    Wdst  = (u16*)   alloc(1024ull * 64 * 2);
  u16*    W1t   = (u16*)   alloc(4096ull * 1024 * 2);
  u16*    W2t   = (u16*)   alloc(1024ull * 4096 * 2);
  u16*    Wfct  = (u16*)   alloc(32000ull * 1024 * 2);

  // ---- prep (every launch; no caching allowed) ----
  gather_k<<<4096, 256, 0, stream>>>(x, emb, h);
  wqkv_k<<<dim3(4, 256), 256, 0, stream>>>(Wq, Wk, Wv, Wqkvt);
  bqkv_k<<<1, 256, 0, stream>>>(bq, bk, bv, bqkv);
  wdsum_k<<<256, 256, 0, stream>>>(Wd, Wdst);
  tcast_k<<<dim3(128, 32), 256, 0, stream>>>(W1, W1t, 1024, 4096);
  tcast_k<<<dim3(32, 128), 256, 0, stream>>>(W2, W2t, 4096, 1024);
  tcast_k<<<dim3(1000, 32), 256, 0, stream>>>(Wfc, Wfct, 1024, 32000);

  for (int layer = 0; layer < 8; ++layer) {
    if (layer == 0)
      ln_k<<<4096, 256, 0, stream>>>(h, g1, be1, z);
    gemm_bt<0><<<dim3(64, 1, 2), 256, 0, stream>>>(z, Wqkvt, partQ, nullptr, nullptr, 1.f,
        512, 1024, 1024, 256, 32, 32, 2, 0, 0, 1048576);
    reduce_qkv<<<1024, 256, 0, stream>>>(partQ, bqkv, qkv, vT);
    flash_k<<<256, 64, 0, stream>>>(qkv, vT, head);
    gemm_bt<1><<<dim3(256, 1, 1), 256, 0, stream>>>(head, Wdst, h, nullptr, bd, 1.f,
        64, 64, 64, 1024, 32, 32, 1, 0, 0, 0);
    ln_k<<<4096, 256, 0, stream>>>(h, g2, be2, z);
    // mid = relu(z2 @ W1 + c1) -- 4-phase engine
    gemm8p<3><<<dim3(256, 1, 1), 512, 131072, stream>>>(z, W1t, nullptr, mid, c1, 1.f,
        1024, 1024, 1024, 4096, 16, 16, 1, 0, 0, 0);
    // partF[sp] = bf16(mid @ W2^T) (split-K x4, K=1024 each) -- 4-phase engine
    gemm8p<2><<<dim3(64, 1, 4), 512, 131072, stream>>>(mid, W2t, nullptr, partF, nullptr, 1.f,
        1024, 4096, 4096, 1024, 16, 16, 4, 0, 0, 4194304);
    if (layer < 7)
      reduce_ln_k<0><<<4096, 256, 0, stream>>>(partF, h, c2, g1, be1, z);
    else
      reduce_ln_k<1><<<4096, 256, 0, stream>>>(partF, h, c2, nullptr, nullptr, z);
  }
  // out = hb @ Wfc + bfc -- 4-phase engine, grouped gm=8
  gemm8p<0><<<dim3(2000, 1, 1), 512, 131072, stream>>>(z, Wfct, out, nullptr, bfc, 1.f,
      1024, 1024, 1024, 32000, 16, 8, 1, 0, 0, 0);
}

// Round 10
// 1557.136 us; speedup vs baseline: 1.2549x; 1.1485x over previous
//
#include <hip/hip_runtime.h>

typedef unsigned short u16;
typedef __attribute__((ext_vector_type(4))) float f32x4;
typedef __attribute__((ext_vector_type(8))) __bf16 bf16x8;
typedef __attribute__((ext_vector_type(4))) unsigned short u16x4;

static __device__ __forceinline__ u16 f2bf(float f) {
  union { float f; unsigned u; } v; v.f = f;
  unsigned r = v.u + 0x7fffu + ((v.u >> 16) & 1u);
  return (u16)(r >> 16);
}

#define GLD_LDS(g, l) __builtin_amdgcn_global_load_lds( \
    (const __attribute__((address_space(1))) void*)(g), \
    (__attribute__((address_space(3))) void*)(l), 16, 0, 0)

// ---------------------------------------------------------------------------
// R5 engine (best measured, frozen): 256x256 BK=64 8-wave, 2-phase/K-tile,
// T2 swizzle (conflicts=0), counted vmcnt(8), setprio. 128 KB LDS.
// EPI: 0 = Cf = alpha*acc + bias; 2 = Cb = bf16(acc+bias); 3 = bf16 relu.
// ---------------------------------------------------------------------------
template<int EPI>
__global__ __launch_bounds__(512, 2)
void gemm8p(const u16* __restrict__ A, const u16* __restrict__ B,
            float* __restrict__ Cf, u16* __restrict__ Cb,
            const float* __restrict__ bias, float alpha,
            int K, int lda, int ldb, int ldc, int mtiles, int gm, int nsplit,
            long long sA, long long sB, long long sC)
{
  extern __shared__ u16 lds8[];
  const int t = threadIdx.x;
  const int w = t >> 6, l = t & 63;
  const int l15 = l & 15, l16 = l >> 4;
  const int wr = w >> 2, wc = w & 3;

  int wg = blockIdx.x;
  const int nwg = gridDim.x;
  {
    const int q = nwg >> 3, r = nwg & 7;
    const int xcd = wg & 7, loc = wg >> 3;
    wg = (xcd < r ? xcd * (q + 1) : r * (q + 1) + (xcd - r) * q) + loc;
  }
  const int ntiles = nwg / mtiles;
  const int gsz = gm * ntiles;
  const int gi = wg / gsz;
  const int rr = wg - gi * gsz;
  const int nt = rr / gm;
  const int mt = gi * gm + (rr - nt * gm);
  const int m0 = mt << 8, n0 = nt << 8;

  const int bz = blockIdx.z;
  int batch = bz, sp = 0;
  if (nsplit > 1) { batch = bz / nsplit; sp = bz - batch * nsplit; }
  const u16* Ab = A + (long long)batch * sA + (long long)sp * K;
  const u16* Bb = B + (long long)batch * sB + (long long)sp * K;
  const long long cbase = (long long)bz * sC;

  const int srow = t >> 3;
  const int scol = (((t & 7) ^ (srow & 7)) << 3);
  const u16* gA[4]; const u16* gB[4];
#pragma unroll
  for (int i = 0; i < 4; ++i) {
    gA[i] = Ab + (long long)(m0 + i * 64 + srow) * lda + scol;
    gB[i] = Bb + (long long)(n0 + i * 64 + srow) * ldb + scol;
  }
  const int ldst = w << 9;

  auto STAGE = [&](int buf) {
#pragma unroll
    for (int i = 0; i < 4; ++i) {
      GLD_LDS(gA[i], &lds8[buf * 16384 + i * 4096 + ldst]);
      gA[i] += 64;
    }
#pragma unroll
    for (int i = 0; i < 4; ++i) {
      GLD_LDS(gB[i], &lds8[32768 + buf * 16384 + i * 4096 + ldst]);
      gB[i] += 64;
    }
  };

  STAGE(0);
  STAGE(1);

  f32x4 acc[8][4] = {};
  const int nkt = K >> 6;
  const int aRow = wr * 128 + l15;
  const int bRow = wc * 64 + l15;
  const int swz = l15 & 7;

  for (int kt = 0; kt < nkt; ++kt) {
    const int buf = kt & 1;
    if (kt < nkt - 1) asm volatile("s_waitcnt vmcnt(8)" ::: "memory");
    else              asm volatile("s_waitcnt vmcnt(0)" ::: "memory");
    __builtin_amdgcn_s_barrier();
    __builtin_amdgcn_sched_barrier(0);

    const int abase = buf * 16384;
    const int bbase = 32768 + buf * 16384;
    bf16x8 af[4][2], bf[4][2];
#pragma unroll
    for (int mf = 0; mf < 4; ++mf)
#pragma unroll
      for (int kk = 0; kk < 2; ++kk)
        af[mf][kk] = *(const bf16x8*)&lds8[abase + (aRow + mf * 16) * 64 + ((((kk << 2) + l16)) ^ swz) * 8];
#pragma unroll
    for (int nf = 0; nf < 4; ++nf)
#pragma unroll
      for (int kk = 0; kk < 2; ++kk)
        bf[nf][kk] = *(const bf16x8*)&lds8[bbase + (bRow + nf * 16) * 64 + ((((kk << 2) + l16)) ^ swz) * 8];

    __builtin_amdgcn_s_setprio(1);
#pragma unroll
    for (int mf = 0; mf < 4; ++mf)
#pragma unroll
      for (int nf = 0; nf < 4; ++nf)
#pragma unroll
        for (int kk = 0; kk < 2; ++kk)
          acc[mf][nf] = __builtin_amdgcn_mfma_f32_16x16x32_bf16(af[mf][kk], bf[nf][kk], acc[mf][nf], 0, 0, 0);
    __builtin_amdgcn_s_setprio(0);

    bf16x8 ah[4][2];
#pragma unroll
    for (int mf = 0; mf < 4; ++mf)
#pragma unroll
      for (int kk = 0; kk < 2; ++kk)
        ah[mf][kk] = *(const bf16x8*)&lds8[abase + (aRow + 64 + mf * 16) * 64 + ((((kk << 2) + l16)) ^ swz) * 8];

    asm volatile("s_waitcnt lgkmcnt(0)" ::: "memory");
    __builtin_amdgcn_s_barrier();
    __builtin_amdgcn_sched_barrier(0);
    if (kt + 2 < nkt) STAGE(buf);

    __builtin_amdgcn_s_setprio(1);
#pragma unroll
    for (int mf = 0; mf < 4; ++mf)
#pragma unroll
      for (int nf = 0; nf < 4; ++nf)
#pragma unroll
        for (int kk = 0; kk < 2; ++kk)
          acc[mf + 4][nf] = __builtin_amdgcn_mfma_f32_16x16x32_bf16(ah[mf][kk], bf[nf][kk], acc[mf + 4][nf], 0, 0, 0);
    __builtin_amdgcn_s_setprio(0);
  }

#pragma unroll
  for (int mf = 0; mf < 8; ++mf) {
    const int rbase = m0 + wr * 128 + mf * 16 + l16 * 4;
#pragma unroll
    for (int nf = 0; nf < 4; ++nf) {
      const int col = n0 + wc * 64 + nf * 16 + l15;
      const float bv = bias ? bias[col] : 0.f;
#pragma unroll
      for (int r = 0; r < 4; ++r) {
        const long long idx = cbase + (long long)(rbase + r) * ldc + col;
        const float v = acc[mf][nf][r];
        if (EPI == 0)      Cf[idx] = alpha * v + bv;
        else if (EPI == 2) Cb[idx] = f2bf(v + bv);
        else               { float x = v + bv; Cb[idx] = f2bf(x > 0.f ? x : 0.f); }
      }
    }
  }
}

// ---- legacy 128x128 engine (small shapes: QKV) ----
template<int EPI>
__global__ __launch_bounds__(256)
void gemm_bt(const u16* __restrict__ A, const u16* __restrict__ B,
             float* __restrict__ Cf, u16* __restrict__ Cb,
             const float* __restrict__ bias, float alpha,
             int K, int lda, int ldb, int ldc, int mtiles, int gm, int nsplit,
             long long sA, long long sB, long long sC)
{
  __shared__ u16 ldsA[128 * 32];
  __shared__ u16 ldsB[128 * 32];
  const int t = threadIdx.x;
  const int w = t >> 6, l = t & 63;

  int wg = blockIdx.x;
  const int nwg = gridDim.x;
  {
    const int q = nwg >> 3, r = nwg & 7;
    const int xcd = wg & 7, loc = wg >> 3;
    wg = (xcd < r ? xcd * (q + 1) : r * (q + 1) + (xcd - r) * q) + loc;
  }
  const int ntiles = nwg / mtiles;
  const int gsz = gm * ntiles;
  const int gi = wg / gsz;
  const int rr = wg - gi * gsz;
  const int nt = rr / gm;
  const int mt = gi * gm + (rr - nt * gm);
  const int m0 = mt << 7, n0 = nt << 7;

  const int bzRaw = blockIdx.z;
  int batch = bzRaw, sp = 0;
  if (nsplit > 1) { batch = bzRaw / nsplit; sp = bzRaw - batch * nsplit; }
  const u16* Ab = A + (long long)batch * sA + (long long)sp * K;
  const u16* Bb = B + (long long)batch * sB + (long long)sp * K;
  const long long cbase = (long long)bzRaw * sC;

  const int wr = (w >> 1) << 6, wc = (w & 1) << 6;
  const int l15 = l & 15, l16 = l >> 4;
  f32x4 acc[4][4] = {};

  for (int k0 = 0; k0 < K; k0 += 32) {
#pragma unroll
    for (int r = 0; r < 2; ++r) {
      const int o = (r << 12) + (t << 4);
      const int row = o >> 6;
      const int cole = (o & 63) >> 1;
      GLD_LDS(Ab + (long long)(m0 + row) * lda + k0 + cole, &ldsA[(r << 11) + (w << 9)]);
      GLD_LDS(Bb + (long long)(n0 + row) * ldb + k0 + cole, &ldsB[(r << 11) + (w << 9)]);
    }
    __syncthreads();
    bf16x8 af[4], bg[4];
#pragma unroll
    for (int i = 0; i < 4; ++i) {
      af[i] = *(const bf16x8*)&ldsA[(wr + i * 16 + l15) * 32 + l16 * 8];
      bg[i] = *(const bf16x8*)&ldsB[(wc + i * 16 + l15) * 32 + l16 * 8];
    }
#pragma unroll
    for (int i = 0; i < 4; ++i)
#pragma unroll
      for (int j = 0; j < 4; ++j)
        acc[i][j] = __builtin_amdgcn_mfma_f32_16x16x32_bf16(af[i], bg[j], acc[i][j], 0, 0, 0);
    __syncthreads();
  }

#pragma unroll
  for (int i = 0; i < 4; ++i) {
    const int rbase = m0 + wr + i * 16 + l16 * 4;
#pragma unroll
    for (int j = 0; j < 4; ++j) {
      const int col = n0 + wc + j * 16 + l15;
      const float bv = bias ? bias[col] : 0.f;
#pragma unroll
      for (int r = 0; r < 4; ++r) {
        const long long idx = cbase + (long long)(rbase + r) * ldc + col;
        const float v = acc[i][j][r];
        if (EPI == 0)      Cf[idx] = alpha * v + bv;
        else if (EPI == 1) Cf[idx] += v + bv;
        else if (EPI == 2) Cb[idx] = f2bf(v + bv);
        else               { float x = v + bv; Cb[idx] = f2bf(x > 0.f ? x : 0.f); }
      }
    }
  }
}

// ---------------- fused flash attention: 4 waves split-KV, in-LDS merge -----
__device__ __forceinline__ void fstep(
    const bf16x8 (&ck)[4][2], const bf16x8 (&cv)[4][2],
    bf16x8 (&nk)[4][2], bf16x8 (&nv)[4][2],
    const bf16x8 (&qf)[2], float (&m)[4], float (&ls)[4], f32x4 (&o)[4],
    const u16* qb, const u16* vb, int kvn, u16* pl, int l15, int l16)
{
  f32x4 s[4] = {};
#pragma unroll
  for (int ni = 0; ni < 4; ++ni)
#pragma unroll
    for (int kk = 0; kk < 2; ++kk)
      s[ni] = __builtin_amdgcn_mfma_f32_16x16x32_bf16(qf[kk], ck[ni][kk], s[ni], 0, 0, 0);
#pragma unroll
  for (int ni = 0; ni < 4; ++ni)
#pragma unroll
    for (int kk = 0; kk < 2; ++kk)
      nk[ni][kk] = *(const bf16x8*)(qb + (kvn + ni * 16 + l15) * 256 + 64 + kk * 32 + l16 * 8);
#pragma unroll
  for (int ni = 0; ni < 4; ++ni) s[ni] *= 0.125f;
  float al[4], ps[4];
#pragma unroll
  for (int r = 0; r < 4; ++r) {
    float v = fmaxf(fmaxf(s[0][r], s[1][r]), fmaxf(s[2][r], s[3][r]));
    v = fmaxf(v, __shfl_xor(v, 1)); v = fmaxf(v, __shfl_xor(v, 2));
    v = fmaxf(v, __shfl_xor(v, 4)); v = fmaxf(v, __shfl_xor(v, 8));
    const float mn = fmaxf(m[r], v);
    al[r] = __expf(m[r] - mn);
    m[r] = mn;
    ps[r] = 0.f;
  }
#pragma unroll
  for (int ni = 0; ni < 4; ++ni)
#pragma unroll
    for (int r = 0; r < 4; ++r) {
      const float p = __expf(s[ni][r] - m[r]);
      ps[r] += p;
      pl[(l16 * 4 + r) * 72 + ni * 16 + l15] = f2bf(p);
    }
#pragma unroll
  for (int r = 0; r < 4; ++r) {
    float t = ps[r];
    t += __shfl_xor(t, 1); t += __shfl_xor(t, 2);
    t += __shfl_xor(t, 4); t += __shfl_xor(t, 8);
    ls[r] = ls[r] * al[r] + t;
  }
#pragma unroll
  for (int nd = 0; nd < 4; ++nd)
#pragma unroll
    for (int r = 0; r < 4; ++r) o[nd][r] *= al[r];
  bf16x8 pa[2];
#pragma unroll
  for (int kk = 0; kk < 2; ++kk)
    pa[kk] = *(const bf16x8*)&pl[l15 * 72 + kk * 32 + l16 * 8];
#pragma unroll
  for (int nd = 0; nd < 4; ++nd)
#pragma unroll
    for (int kk = 0; kk < 2; ++kk)
      o[nd] = __builtin_amdgcn_mfma_f32_16x16x32_bf16(pa[kk], cv[nd][kk], o[nd], 0, 0, 0);
#pragma unroll
  for (int nd = 0; nd < 4; ++nd)
#pragma unroll
    for (int kk = 0; kk < 2; ++kk)
      nv[nd][kk] = *(const bf16x8*)(vb + (nd * 16 + l15) * 2048 + kvn + kk * 32 + l16 * 8);
}

// grid 256 = b(2) x qt(128); 4 waves, wave sp covers kv [sp*512, +512).
// LSE-merge in LDS; single head write. No global partials.
__global__ __launch_bounds__(256)
void flash4_k(const u16* __restrict__ qkv, const u16* __restrict__ vT,
              u16* __restrict__ head)
{
  __shared__ u16 plbuf[4][16 * 72];
  __shared__ float poL[4][16][64];
  __shared__ float pmL[4][16], plsL[4][16];
  const int t = threadIdx.x, sp = t >> 6, l = t & 63;
  const int l15 = l & 15, l16 = l >> 4;
  const int b = blockIdx.x >> 7, q0 = (blockIdx.x & 127) << 4;
  const int kvb = sp << 9;
  const u16* qb = qkv + (long long)b * 2048 * 256;
  const u16* vb = vT + (long long)b * 64 * 2048;
  u16* pl = &plbuf[sp][0];
  bf16x8 qf[2];
#pragma unroll
  for (int kk = 0; kk < 2; ++kk)
    qf[kk] = *(const bf16x8*)(qb + (q0 + l15) * 256 + kk * 32 + l16 * 8);
  float m[4], ls[4];
  f32x4 o[4] = {};
#pragma unroll
  for (int r = 0; r < 4; ++r) { m[r] = -1e30f; ls[r] = 0.f; }
  bf16x8 ka[4][2], va[4][2], kb[4][2], vb2[4][2];
#pragma unroll
  for (int ni = 0; ni < 4; ++ni)
#pragma unroll
    for (int kk = 0; kk < 2; ++kk) {
      ka[ni][kk] = *(const bf16x8*)(qb + (kvb + ni * 16 + l15) * 256 + 64 + kk * 32 + l16 * 8);
      va[ni][kk] = *(const bf16x8*)(vb + (ni * 16 + l15) * 2048 + kvb + kk * 32 + l16 * 8);
    }
  for (int ti = 0; ti < 8; ti += 2) {
    const int n1 = kvb + (ti + 1 < 8 ? (ti + 1) * 64 : 7 * 64);
    const int n2 = kvb + (ti + 2 < 8 ? (ti + 2) * 64 : 7 * 64);
    fstep(ka, va, kb, vb2, qf, m, ls, o, qb, vb, n1, pl, l15, l16);
    fstep(kb, vb2, ka, va, qf, m, ls, o, qb, vb, n2, pl, l15, l16);
  }
  // partials -> LDS
#pragma unroll
  for (int nd = 0; nd < 4; ++nd)
#pragma unroll
    for (int r = 0; r < 4; ++r)
      poL[sp][l16 * 4 + r][nd * 16 + l15] = o[nd][r];
  if (l15 == 0) {
#pragma unroll
    for (int r = 0; r < 4; ++r) {
      pmL[sp][l16 * 4 + r] = m[r];
      plsL[sp][l16 * 4 + r] = ls[r];
    }
  }
  __syncthreads();
  // merge: thread t handles 4 of the 16x64 outputs
#pragma unroll
  for (int i = 0; i < 4; ++i) {
    const int oi = t + i * 256;
    const int row = oi >> 6, col = oi & 63;
    float M = fmaxf(fmaxf(pmL[0][row], pmL[1][row]), fmaxf(pmL[2][row], pmL[3][row]));
    float L = 0.f, acc = 0.f;
#pragma unroll
    for (int s2 = 0; s2 < 4; ++s2) {
      const float e = __expf(pmL[s2][row] - M);
      L += plsL[s2][row] * e;
      acc += poL[s2][row][col] * e;
    }
    head[((long long)b * 2048 + q0 + row) * 64 + col] = f2bf(acc / L);
  }
}

// ---------------- fused head@Wdsum + bias + residual + LN2 ------------------
// grid 256 (16 h-rows each), 4 waves; wave w owns cols w*256..+255.
// Wdst[e][a] (1024x64 bf16, L2-resident). h += head@Wdsum^T + bd ; z = LN(h).
__global__ __launch_bounds__(256)
void hwd_ln_k(const u16* __restrict__ head, const u16* __restrict__ Wdst,
              const float* __restrict__ bd, float* __restrict__ h,
              const float* __restrict__ g, const float* __restrict__ be,
              u16* __restrict__ z)
{
  const int t = threadIdx.x, w = t >> 6, l = t & 63;
  const int l15 = l & 15, l16 = l >> 4;
  const int r0 = blockIdx.x << 4;
  const int c0 = w << 8;
  bf16x8 af[2];
#pragma unroll
  for (int kk = 0; kk < 2; ++kk)
    af[kk] = *(const bf16x8*)&head[(long long)(r0 + l15) * 64 + kk * 32 + l16 * 8];
  f32x4 acc[16];
#pragma unroll
  for (int nf = 0; nf < 16; ++nf) {
    const int e = c0 + nf * 16 + l15;
    f32x4 a = {0.f, 0.f, 0.f, 0.f};
    bf16x8 b0 = *(const bf16x8*)&Wdst[e * 64 + l16 * 8];
    bf16x8 b1 = *(const bf16x8*)&Wdst[e * 64 + 32 + l16 * 8];
    a = __builtin_amdgcn_mfma_f32_16x16x32_bf16(af[0], b0, a, 0, 0, 0);
    a = __builtin_amdgcn_mfma_f32_16x16x32_bf16(af[1], b1, a, 0, 0, 0);
    acc[nf] = a;
  }
  float ps[4] = {0.f, 0.f, 0.f, 0.f}, pq[4] = {0.f, 0.f, 0.f, 0.f};
#pragma unroll
  for (int nf = 0; nf < 16; ++nf) {
    const int col = c0 + nf * 16 + l15;
#pragma unroll
    for (int r = 0; r < 4; ++r) {
      const long long row = r0 + l16 * 4 + r;
      float v = h[row * 1024 + col] + acc[nf][r] + bd[col];
      acc[nf][r] = v;
      ps[r] += v; pq[r] += v * v;
    }
  }
#pragma unroll
  for (int r = 0; r < 4; ++r) {
#pragma unroll
    for (int msk = 1; msk < 16; msk <<= 1) {
      ps[r] += __shfl_xor(ps[r], msk);
      pq[r] += __shfl_xor(pq[r], msk);
    }
  }
  __shared__ float S[4][16], Q[4][16];
  if (l15 == 0) {
#pragma unroll
    for (int r = 0; r < 4; ++r) { S[w][l16 * 4 + r] = ps[r]; Q[w][l16 * 4 + r] = pq[r]; }
  }
  __syncthreads();
  float mu[4], rstd[4];
#pragma unroll
  for (int r = 0; r < 4; ++r) {
    const int ri = l16 * 4 + r;
    const float s = S[0][ri] + S[1][ri] + S[2][ri] + S[3][ri];
    const float q = Q[0][ri] + Q[1][ri] + Q[2][ri] + Q[3][ri];
    mu[r] = s * (1.f / 1024.f);
    rstd[r] = rsqrtf(q * (1.f / 1024.f) - mu[r] * mu[r] + 1e-5f);
  }
#pragma unroll
  for (int nf = 0; nf < 16; ++nf) {
    const int col = c0 + nf * 16 + l15;
    const float gc = g[col], bc = be[col];
#pragma unroll
    for (int r = 0; r < 4; ++r) {
      const long long row = r0 + l16 * 4 + r;
      h[row * 1024 + col] = acc[nf][r];
      z[row * 1024 + col] = f2bf((acc[nf][r] - mu[r]) * rstd[r] * gc + bc);
    }
  }
}

// LayerNorm over rows of 1024 f32 -> bf16 out (layer-0 only)
__global__ __launch_bounds__(256)
void ln_k(const float* __restrict__ x, const float* __restrict__ g,
          const float* __restrict__ b, u16* __restrict__ z)
{
  const long long row = blockIdx.x;
  f32x4 v = ((const f32x4*)(x + row * 1024))[threadIdx.x];
  float s = v[0] + v[1] + v[2] + v[3];
  float q = v[0] * v[0] + v[1] * v[1] + v[2] * v[2] + v[3] * v[3];
#pragma unroll
  for (int o = 32; o; o >>= 1) { s += __shfl_down(s, o); q += __shfl_down(q, o); }
  __shared__ float rs_[4], rq_[4];
  const int l = threadIdx.x & 63, w = threadIdx.x >> 6;
  if (l == 0) { rs_[w] = s; rq_[w] = q; }
  __syncthreads();
  s = rs_[0] + rs_[1] + rs_[2] + rs_[3];
  q = rq_[0] + rq_[1] + rq_[2] + rq_[3];
  const float mu = s * (1.f / 1024.f);
  const float rstd = rsqrtf(q * (1.f / 1024.f) - mu * mu + 1e-5f);
  const f32x4 gv = ((const f32x4*)g)[threadIdx.x];
  const f32x4 bv = ((const f32x4*)b)[threadIdx.x];
  u16x4 o4;
#pragma unroll
  for (int e = 0; e < 4; ++e) o4[e] = f2bf((v[e] - mu) * rstd * gv[e] + bv[e]);
  ((u16x4*)(z + row * 1024))[threadIdx.x] = o4;
}

// fused: hnew = h + sum_{s<4} bf16partial_s + c2 ; MODE0: h=hnew, z=LN(hnew);
// MODE1: z=bf16(hnew) (h dead)
template<int MODE>
__global__ __launch_bounds__(256)
void reduce_ln_k(const u16* __restrict__ p, float* __restrict__ h,
                 const float* __restrict__ c2, const float* __restrict__ g,
                 const float* __restrict__ b, u16* __restrict__ z)
{
  const long long row = blockIdx.x;
  const int t = threadIdx.x;
  const long long i4 = (row << 8) + t;
  f32x4 v = ((const f32x4*)h)[i4] + ((const f32x4*)c2)[t];
#pragma unroll
  for (int s = 0; s < 4; ++s) {
    u16x4 pv = ((const u16x4*)p)[i4 + (long long)s * 1048576];
#pragma unroll
    for (int e = 0; e < 4; ++e) {
      union { unsigned u; float f; } x; x.u = ((unsigned)pv[e]) << 16;
      v[e] += x.f;
    }
  }
  u16x4 o4;
  if (MODE == 1) {
#pragma unroll
    for (int e = 0; e < 4; ++e) o4[e] = f2bf(v[e]);
  } else {
    ((f32x4*)h)[i4] = v;
    float s = v[0] + v[1] + v[2] + v[3];
    float q = v[0] * v[0] + v[1] * v[1] + v[2] * v[2] + v[3] * v[3];
#pragma unroll
    for (int o = 32; o; o >>= 1) { s += __shfl_down(s, o); q += __shfl_down(q, o); }
    __shared__ float rs_[4], rq_[4];
    const int l = t & 63, w = t >> 6;
    if (l == 0) { rs_[w] = s; rq_[w] = q; }
    __syncthreads();
    s = rs_[0] + rs_[1] + rs_[2] + rs_[3];
    q = rq_[0] + rq_[1] + rq_[2] + rq_[3];
    const float mu = s * (1.f / 1024.f);
    const float rstd = rsqrtf(q * (1.f / 1024.f) - mu * mu + 1e-5f);
    const f32x4 gv = ((const f32x4*)g)[t];
    const f32x4 bv = ((const f32x4*)b)[t];
#pragma unroll
    for (int e = 0; e < 4; ++e) o4[e] = f2bf((v[e] - mu) * rstd * gv[e] + bv[e]);
  }
  ((u16x4*)z)[i4] = o4;
}

__global__ __launch_bounds__(256)
void gather_k(const int* __restrict__ x, const float* __restrict__ emb, float* __restrict__ h)
{
  const long long tok = blockIdx.x;
  const long long r = (long long)x[tok] << 8;
  ((f32x4*)h)[(tok << 8) + threadIdx.x] = ((const f32x4*)emb)[r + threadIdx.x];
}

// f32 [R][C] -> bf16 [C][R]
__global__ __launch_bounds__(256)
void tcast_k(const float* __restrict__ in, u16* __restrict__ out, int R, int C)
{
  __shared__ float tile[32][33];
  const int tx = threadIdx.x & 31, ty = threadIdx.x >> 5;
  const long long r0 = (long long)blockIdx.y << 5, c0 = (long long)blockIdx.x << 5;
#pragma unroll
  for (int yy = 0; yy < 32; yy += 8)
    tile[ty + yy][tx] = in[(r0 + ty + yy) * C + c0 + tx];
  __syncthreads();
#pragma unroll
  for (int yy = 0; yy < 32; yy += 8)
    out[(c0 + ty + yy) * R + r0 + tx] = f2bf(tile[tx][ty + yy]);
}

__global__ __launch_bounds__(256)
void wqkv_k(const float* __restrict__ Wq, const float* __restrict__ Wk,
            const float* __restrict__ Wv, u16* __restrict__ o)
{
  const int n = blockIdx.y;
  const long long e = (long long)blockIdx.x * 256 + threadIdx.x;
  float v = 0.f;
  if (n < 64)       v = Wq[e * 64 + n];
  else if (n < 128) v = Wk[e * 64 + (n - 64)];
  else if (n < 192) v = Wv[e * 64 + (n - 128)];
  o[(long long)n * 1024 + e] = f2bf(v);
}

__global__ __launch_bounds__(256)
void bqkv_k(const float* __restrict__ bq, const float* __restrict__ bk,
            const float* __restrict__ bv, float* __restrict__ o)
{
  const int n = threadIdx.x;
  float v = 0.f;
  if (n < 64)       v = bq[n];
  else if (n < 128) v = bk[n - 64];
  else if (n < 192) v = bv[n - 128];
  o[n] = v;
}

__global__ __launch_bounds__(256)
void wdsum_k(const float* __restrict__ Wd, u16* __restrict__ o)
{
  const int i = blockIdx.x * 256 + threadIdx.x;
  const int a = i & 63, e = i >> 6;
  float s = 0.f;
#pragma unroll
  for (int hh = 0; hh < 16; ++hh) s += Wd[(long long)(hh * 64 + a) * 1024 + e];
  o[i] = f2bf(s);
}

// qkv = bf16(p0+p1+bqkv), plus vT scatter for v-cols [128,192) -> vT[b*64+a][2048]
__global__ __launch_bounds__(256)
void reduce_qkv(const float* __restrict__ p, const float* __restrict__ bqkv,
                u16* __restrict__ qkv, u16* __restrict__ vT)
{
  const long long i4 = (long long)blockIdx.x * 256 + threadIdx.x;
  const int c4 = (int)(i4 & 63);
  const long long row = i4 >> 6;
  f32x4 s = ((const f32x4*)p)[i4] + ((const f32x4*)p)[i4 + 262144]
          + ((const f32x4*)bqkv)[c4];
  u16x4 o;
#pragma unroll
  for (int e = 0; e < 4; ++e) o[e] = f2bf(s[e]);
  ((u16x4*)qkv)[i4] = o;
  if (c4 >= 32 && c4 < 48) {
    const long long b = row >> 11, sidx = row & 2047;
#pragma unroll
    for (int e = 0; e < 4; ++e) {
      const int a = (c4 - 32) * 4 + e;
      vT[(b * 64 + a) * 2048 + sidx] = o[e];
    }
  }
}

extern "C" void kernel_launch(void* const* d_in, const int* in_sizes, int n_in,
                              void* d_out, int out_size, void* d_ws, size_t ws_size,
                              hipStream_t stream) {
  const int*   x   = (const int*)d_in[0];
  const float* emb = (const float*)d_in[1];
  const float* Wq  = (const float*)d_in[2];
  const float* bq  = (const float*)d_in[3];
  const float* Wk  = (const float*)d_in[4];
  const float* bk  = (const float*)d_in[5];
  const float* Wv  = (const float*)d_in[6];
  const float* bv  = (const float*)d_in[7];
  const float* Wd  = (const float*)d_in[8];
  const float* bd  = (const float*)d_in[9];
  const float* g1  = (const float*)d_in[10];
  const float* be1 = (const float*)d_in[11];
  const float* g2  = (const float*)d_in[12];
  const float* be2 = (const float*)d_in[13];
  const float* W1  = (const float*)d_in[14];
  const float* c1  = (const float*)d_in[15];
  const float* W2  = (const float*)d_in[16];
  const float* c2  = (const float*)d_in[17];
  const float* Wfc = (const float*)d_in[18];
  const float* bfc = (const float*)d_in[19];
  float* out = (float*)d_out;

  hipFuncSetAttribute(reinterpret_cast<const void*>(gemm8p<0>),
                      hipFuncAttributeMaxDynamicSharedMemorySize, 131072);
  hipFuncSetAttribute(reinterpret_cast<const void*>(gemm8p<2>),
                      hipFuncAttributeMaxDynamicSharedMemorySize, 131072);
  hipFuncSetAttribute(reinterpret_cast<const void*>(gemm8p<3>),
                      hipFuncAttributeMaxDynamicSharedMemorySize, 131072);

  char* ws = (char*)d_ws;
  size_t off = 0;
  auto alloc = [&](size_t bytes) { void* p = ws + off; off = (off + bytes + 255) & ~(size_t)255; return p; };
  float*  h     = (float*) alloc(4096ull * 1024 * 4);
  u16*    z     = (u16*)   alloc(4096ull * 1024 * 2);
  u16*    qkv   = (u16*)   alloc(4096ull * 256 * 2);
  u16*    vT    = (u16*)   alloc(2ull * 64 * 2048 * 2);
  u16*    head  = (u16*)   alloc(4096ull * 64 * 2);
  u16*    mid   = (u16*)   alloc(4096ull * 4096 * 2);
  // SCR aliasing (lifetimes disjoint): partQ [QKV->reduce]; partF [FFN2->reduce_ln]
  char*   SCR   = (char*)  alloc(2ull * 4096 * 1024 * 4);
  float*  partQ = (float*)SCR;
  u16*    partF = (u16*)SCR;
  u16*    Wqkvt = (u16*)   alloc(256ull * 1024 * 2);
  float*  bqkv  = (float*) alloc(256 * 4);
  u16*    Wdst  = (u16*)   alloc(1024ull * 64 * 2);
  u16*    W1t   = (u16*)   alloc(4096ull * 1024 * 2);
  u16*    W2t   = (u16*)   alloc(1024ull * 4096 * 2);
  u16*    Wfct  = (u16*)   alloc(32000ull * 1024 * 2);

  // ---- prep (every launch; no caching allowed) ----
  gather_k<<<4096, 256, 0, stream>>>(x, emb, h);
  wqkv_k<<<dim3(4, 256), 256, 0, stream>>>(Wq, Wk, Wv, Wqkvt);
  bqkv_k<<<1, 256, 0, stream>>>(bq, bk, bv, bqkv);
  wdsum_k<<<256, 256, 0, stream>>>(Wd, Wdst);
  tcast_k<<<dim3(128, 32), 256, 0, stream>>>(W1, W1t, 1024, 4096);
  tcast_k<<<dim3(32, 128), 256, 0, stream>>>(W2, W2t, 4096, 1024);
  tcast_k<<<dim3(1000, 32), 256, 0, stream>>>(Wfc, Wfct, 1024, 32000);

  for (int layer = 0; layer < 8; ++layer) {
    if (layer == 0)
      ln_k<<<4096, 256, 0, stream>>>(h, g1, be1, z);
    gemm_bt<0><<<dim3(64, 1, 2), 256, 0, stream>>>(z, Wqkvt, partQ, nullptr, nullptr, 1.f,
        512, 1024, 1024, 256, 32, 32, 2, 0, 0, 1048576);
    reduce_qkv<<<1024, 256, 0, stream>>>(partQ, bqkv, qkv, vT);
    // fused attention: 4-wave split-KV, in-LDS LSE merge
    flash4_k<<<256, 256, 0, stream>>>(qkv, vT, head);
    // fused: h += head@Wdsum^T + bd ; z = LN2(h)
    hwd_ln_k<<<256, 256, 0, stream>>>(head, Wdst, bd, h, g2, be2, z);
    // mid = relu(z2 @ W1 + c1) -- R5 engine
    gemm8p<3><<<dim3(256, 1, 1), 512, 131072, stream>>>(z, W1t, nullptr, mid, c1, 1.f,
        1024, 1024, 1024, 4096, 16, 16, 1, 0, 0, 0);
    // partF[sp] = bf16(mid @ W2^T) (split-K x4, K=1024 each) -- R5 engine
    gemm8p<2><<<dim3(64, 1, 4), 512, 131072, stream>>>(mid, W2t, nullptr, partF, nullptr, 1.f,
        1024, 4096, 4096, 1024, 16, 16, 4, 0, 0, 4194304);
    if (layer < 7)
      reduce_ln_k<0><<<4096, 256, 0, stream>>>(partF, h, c2, g1, be1, z);
    else
      reduce_ln_k<1><<<4096, 256, 0, stream>>>(partF, h, c2, nullptr, nullptr, z);
  }
  // out = hb @ Wfc + bfc -- R5 engine, grouped gm=8
  gemm8p<0><<<dim3(2000, 1, 1), 512, 131072, stream>>>(z, Wfct, out, nullptr, bfc, 1.f,
      1024, 1024, 1024, 32000, 16, 8, 1, 0, 0, 0);
}